// Round 3
// baseline (7859.138 us; speedup 1.0000x reference)
//
#include <hip/hip_runtime.h>
#include <math.h>
#include <stddef.h>

// ---------------------------------------------------------------------------
// ATT_SYN: bi-LSTM encoder + synopsis attention + 2nd bi-LSTM + tag head.
// B=8 T=512 S=32 J=64 D=400 R=256 MDU=100 TAGS=7
// Recurrence: cooperative kernel, 4 slice-WGs per batch group; each WG owns
// gate cols s*64..s*64+63 for BOTH directions (bw[2][4][8] resident in the
// unified VGPR/AGPR file) and alternates dir0/dir1 phases per step, so each
// direction's flag-visibility + h-reload round trip is hidden under the
// other direction's compute+drain. Per-step sync: per-(dir,WG) flag slots,
// all-lane relaxed poll + acquire FENCE (no extra RT, no post-spin barrier).
// ---------------------------------------------------------------------------

#define BB 8
#define TT 512
#define SS 32
#define JJ 64
#define DD 400
#define RR 256
#define G4 1024
#define H2 512
#define MDU_ 100
#define TAGS_ 7
#define BT (BB*TT)
#define NSEQ (BB*SS)
#define SCH 64
#define MB1 (1024*1024)

typedef __attribute__((ext_vector_type(8))) short short8;
typedef __attribute__((ext_vector_type(4))) float floatx4;
typedef __attribute__((ext_vector_type(4))) unsigned int u32x4;
typedef unsigned short u16;
typedef unsigned int u32;

__device__ __forceinline__ float us2f(u16 u) {
    unsigned int v = ((unsigned int)u) << 16;
    return __builtin_bit_cast(float, v);
}
__device__ __forceinline__ u16 f2us(float f) {
    unsigned int v = __builtin_bit_cast(unsigned int, f);
    v += 0x7FFFu + ((v >> 16) & 1u);
    return (u16)(v >> 16);
}
__device__ __forceinline__ float ldin(const void* p, long i, int bf) {
    return bf ? us2f(((const u16*)p)[i]) : ((const float*)p)[i];
}
__device__ __forceinline__ float sigm(float x) { return 1.0f / (1.0f + expf(-x)); }
// fast activations for the recurrence critical path (NaN-safe)
__device__ __forceinline__ float sigm_f(float x) { return 1.0f / (1.0f + __expf(-x)); }
__device__ __forceinline__ float tanh_f(float x) {
    float e = __expf(-2.0f * fabsf(x));
    float t = (1.0f - e) / (1.0f + e);
    return copysignf(t, x);
}

// ---- dtype probe ----
__global__ void detect_k(const void* x, int* flag) {
    __shared__ int cnt;
    if (threadIdx.x == 0) cnt = 0;
    __syncthreads();
    u16 lo = ((const u16*)x)[threadIdx.x * 2];
    int e = (lo >> 7) & 0xFF;
    if (e >= 118 && e <= 131) atomicAdd(&cnt, 1);
    __syncthreads();
    if (threadIdx.x == 0) *flag = (cnt > 128) ? 1 : 0;
}
__global__ void castbf_k(const void* src, long off, u16* dst, long n, const int* flag) {
    long i = (long)blockIdx.x * 256 + threadIdx.x;
    if (i < n) dst[i] = (*flag) ? ((const u16*)src)[off + i] : f2us(((const float*)src)[off + i]);
}
__global__ void castf_k(const void* src, float* dst, long n, const int* flag) {
    long i = (long)blockIdx.x * 256 + threadIdx.x;
    if (i < n) dst[i] = ldin(src, i, *flag);
}
__global__ void zero_k(u32* p, long n) {
    long i = (long)blockIdx.x * 256 + threadIdx.x;
    if (i < n) p[i] = 0u;
}
__global__ void bias_sum_k(const void* bih, const void* bhh, float* out, const int* flag) {
    int i = blockIdx.x * 256 + threadIdx.x;
    if (i < G4) out[i] = ldin(bih, i, *flag) + ldin(bhh, i, *flag);
}
__global__ void wsum_k(const void* a, const void* b, u16* o, const int* flag) {
    int i = blockIdx.x * 256 + threadIdx.x;
    if (i < H2 * H2) o[i] = f2us(ldin(a, i, *flag) + ldin(b, i, *flag));
}
// Whh [1024,256] -> pre-swizzled MFMA B-fragments (4-slice partition):
// WF[((((s*4+w)*4+t)*8+c)*64+lane)*8+j] = Whh[(w*256+s*64+t*16+(lane&15))*256
//                                              + c*32+(lane>>4)*8+j]
__global__ void whh_frag_k(const void* Whh, u16* WF, const int* flag) {
    int i = blockIdx.x * 256 + threadIdx.x;
    if (i >= 4 * 4 * 4 * 8 * 64 * 8) return;
    int j  = i & 7;
    int ln = (i >> 3) & 63;
    int c  = (i >> 9) & 7;
    int t  = (i >> 12) & 3;
    int w  = (i >> 14) & 3;
    int s  = (i >> 16) & 3;
    int n_g = w * 256 + s * 64 + t * 16 + (ln & 15);
    int k   = c * 32 + (ln >> 4) * 8 + j;
    WF[i] = f2us(ldin(Whh, (long)n_g * 256 + k, *flag));
}

// ---------------------------------------------------------------------------
// GEMM: C[M,N] = A[M,K] @ W[N,K]^T (+bias); A,W bf16; C f32 or bf16.
// ---------------------------------------------------------------------------
#define BM 128
#define BN 128
#define BK 32
#define LDT 40

__global__ __launch_bounds__(256)
void gemm_bt(const u16* __restrict__ A, int lda,
             const u16* __restrict__ W, int ldw,
             void* __restrict__ C, int ldc,
             const float* __restrict__ bias,
             int M, int N, int K, int outBf16)
{
    __shared__ alignas(16) short As[BM * LDT];
    __shared__ alignas(16) short Bs[BN * LDT];
    const int tid  = threadIdx.x;
    const int m0   = blockIdx.y * BM;
    const int n0   = blockIdx.x * BN;
    const int lane = tid & 63;
    const int wave = tid >> 6;
    const int wm   = wave >> 1, wn = wave & 1;
    const int quad = lane >> 4, mrow = lane & 15;

    floatx4 acc[4][4];
#pragma unroll
    for (int i = 0; i < 4; ++i)
#pragma unroll
        for (int j = 0; j < 4; ++j) { floatx4 z4 = {0.f,0.f,0.f,0.f}; acc[i][j] = z4; }

    for (int k0 = 0; k0 < K; k0 += BK) {
#pragma unroll
        for (int cc = 0; cc < 2; ++cc) {
            int c   = tid + cc * 256;
            int row = c >> 2;
            int kc  = (c & 3) << 3;
            int gk  = k0 + kc;
            {
                int gr = m0 + row;
                short8 v;
                if (gr < M && gk + 8 <= K) {
                    v = *(const short8*)(A + (size_t)gr * lda + gk);
                } else {
#pragma unroll
                    for (int e = 0; e < 8; ++e)
                        v[e] = (gr < M && (gk + e) < K) ? (short)A[(size_t)gr * lda + gk + e] : (short)0;
                }
                *(short8*)&As[row * LDT + kc] = v;
            }
            {
                int gn = n0 + row;
                short8 v;
                if (gn < N && gk + 8 <= K) {
                    v = *(const short8*)(W + (size_t)gn * ldw + gk);
                } else {
#pragma unroll
                    for (int e = 0; e < 8; ++e)
                        v[e] = (gn < N && (gk + e) < K) ? (short)W[(size_t)gn * ldw + gk + e] : (short)0;
                }
                *(short8*)&Bs[row * LDT + kc] = v;
            }
        }
        __syncthreads();

        short8 af[4], bf[4];
#pragma unroll
        for (int i = 0; i < 4; ++i)
            af[i] = *(const short8*)&As[(wm * 64 + i * 16 + mrow) * LDT + quad * 8];
#pragma unroll
        for (int j = 0; j < 4; ++j)
            bf[j] = *(const short8*)&Bs[(wn * 64 + j * 16 + mrow) * LDT + quad * 8];
#pragma unroll
        for (int i = 0; i < 4; ++i)
#pragma unroll
            for (int j = 0; j < 4; ++j)
                acc[i][j] = __builtin_amdgcn_mfma_f32_16x16x32_bf16(af[i], bf[j], acc[i][j], 0, 0, 0);
        __syncthreads();
    }

#pragma unroll
    for (int i = 0; i < 4; ++i)
#pragma unroll
        for (int j = 0; j < 4; ++j)
#pragma unroll
            for (int r = 0; r < 4; ++r) {
                int row = m0 + wm * 64 + i * 16 + quad * 4 + r;
                int col = n0 + wn * 64 + j * 16 + mrow;
                if (row < M && col < N) {
                    float v = acc[i][j][r];
                    if (bias) v += bias[col];
                    if (outBf16) ((u16*)C)[(size_t)row * ldc + col] = f2us(v);
                    else         ((float*)C)[(size_t)row * ldc + col] = v;
                }
            }
}

// ---------------------------------------------------------------------------
// Cooperative dual-direction LSTM. Grid (4 slices, nbatch). Group = batch of
// 4 slice-WGs; each WG: 256 thr (4 waves), wave w = gate type, holds its
// 64x256 bf16 Whh slice for BOTH dirs in 256 reg-equivalents (unified
// VGPR/AGPR). M=8 seqs/WG. Per step: dir0 phase then dir1 phase; each
// phase's exchange RT is hidden under the other phase's compute.
// Flags: flg[d*4+s] = step count; all-lane relaxed poll + acquire fence.
// hx: per group [dir][parity][8 seq][128 u32].
// ---------------------------------------------------------------------------
__global__ __launch_bounds__(256, 1)
void lstm_coop(const u16* __restrict__ xWf, const u16* __restrict__ xWb,
               const u16* __restrict__ WFf, const u16* __restrict__ WFb,
               int L,
               u16* __restrict__ hOut, int hStride,
               u16* __restrict__ cOut, int cStride,
               const int* __restrict__ lenp,
               int writeAtSource, int lastOnly, int seqBase,
               u32* __restrict__ hx32, u32* __restrict__ flags, int grpBase)
{
    const int s   = blockIdx.x;        // slice (owns gate cols s*64..s*64+63)
    const int bat = blockIdx.y;
    const int tid = threadIdx.x;
    const int wv  = tid >> 6;          // gate type i,f,g,o
    const int ln  = tid & 63;
    const int q   = ln >> 4, m = ln & 15;
    const int grp = grpBase + bat;
    u32* flg = flags + (size_t)grp * 16;    // slots [d*4+s]
    u32* hxg = hx32 + (size_t)grp * 4096;   // [dir][2][8 seq][128 u32]

    __shared__ float g_s[4 * 8 * 64];
    __shared__ float c_s[2][8 * 64];

    // resident B fragments for both dirs: 2 x 4 N-tiles x 8 K-chunks
    short8 bw[2][4][8];
#pragma unroll
    for (int d = 0; d < 2; ++d) {
        const u16* wb = (d ? WFb : WFf) + ((size_t)(s * 4 + wv) * 32) * 512 + ln * 8;
#pragma unroll
        for (int t4 = 0; t4 < 4; ++t4)
#pragma unroll
            for (int c = 0; c < 8; ++c)
                bw[d][t4][c] = *(const short8*)(wb + (size_t)(t4 * 8 + c) * 512);
    }
    for (int i = tid; i < 1024; i += 256) ((float*)c_s)[i] = 0.f;
    __syncthreads();

    const int seqU = tid >> 5;             // update phase: seq 0..7
    const int j0   = (tid & 31) * 2;       // local col pair within slice
    const int gcol = s * 64 + j0;          // global gate col
    const int mylen = lenp ? lenp[bat * 8 + seqU] : 0x7fffffff;

    // preload x gate values for t=0, both dirs
    u32 px[2][4];
#pragma unroll
    for (int d = 0; d < 2; ++d) {
        const int tt0 = d ? (L - 1) : 0;
        const u16* xr = (d ? xWb : xWf) + (((size_t)(bat * 8 + seqU)) * L + tt0) * G4 + gcol;
        px[d][0] = *(const u32*)xr;
        px[d][1] = *(const u32*)(xr + 256);
        px[d][2] = *(const u32*)(xr + 512);
        px[d][3] = *(const u32*)(xr + 768);
    }

    for (int t = 0; t < L; ++t) {
        const bool last = (t == L - 1);
#pragma unroll
        for (int d = 0; d < 2; ++d) {
            const int tt = d ? (L - 1 - t) : t;
            // ---- wait for partner h of this dir (all lanes poll; no RT tail)
            if (t > 0) {
                const u32 tgt = (u32)t;
                long guard = 0;
                for (;;) {
                    u32 f0 = __hip_atomic_load(&flg[d * 4 + 0], __ATOMIC_RELAXED, __HIP_MEMORY_SCOPE_AGENT);
                    u32 f1 = __hip_atomic_load(&flg[d * 4 + 1], __ATOMIC_RELAXED, __HIP_MEMORY_SCOPE_AGENT);
                    u32 f2 = __hip_atomic_load(&flg[d * 4 + 2], __ATOMIC_RELAXED, __HIP_MEMORY_SCOPE_AGENT);
                    u32 f3 = __hip_atomic_load(&flg[d * 4 + 3], __ATOMIC_RELAXED, __HIP_MEMORY_SCOPE_AGENT);
                    if (f0 >= tgt && f1 >= tgt && f2 >= tgt && f3 >= tgt) break;
                    if (++guard > (1L << 18)) break;   // diagnostic bail
                    if (guard > 16) __builtin_amdgcn_s_sleep(1);
                }
                // acquire fence: cache-inv only, no extra memory round trip
                __atomic_thread_fence(__ATOMIC_ACQUIRE);
            }
            // ---- A fragments from hxg[d][(t-1)&1]
            short8 a[8];
            if (t > 0) {
                const u32* hp = hxg + d * 2048 + ((t - 1) & 1) * 1024 + m * 128;
#pragma unroll
                for (int c = 0; c < 8; ++c) {
                    if (m < 8) {
                        u32x4 v = *(const u32x4*)(hp + c * 16 + q * 4);
                        a[c] = __builtin_bit_cast(short8, v);
                    } else {
                        short8 z = {0,0,0,0,0,0,0,0}; a[c] = z;
                    }
                }
            } else {
                short8 z = {0,0,0,0,0,0,0,0};
#pragma unroll
                for (int c = 0; c < 8; ++c) a[c] = z;
            }
            floatx4 acc[4];
#pragma unroll
            for (int t4 = 0; t4 < 4; ++t4) { floatx4 z4 = {0.f,0.f,0.f,0.f}; acc[t4] = z4; }
#pragma unroll
            for (int c = 0; c < 8; ++c)
#pragma unroll
                for (int t4 = 0; t4 < 4; ++t4)
                    acc[t4] = __builtin_amdgcn_mfma_f32_16x16x32_bf16(a[c], bw[d][t4][c], acc[t4], 0, 0, 0);
            // C layout: seq = q*4+r (valid q<2), col n = t4*16 + m
            if (q < 2) {
#pragma unroll
                for (int t4 = 0; t4 < 4; ++t4)
#pragma unroll
                    for (int r = 0; r < 4; ++r)
                        g_s[(wv * 8 + q * 4 + r) * 64 + t4 * 16 + m] = acc[t4][r];
            }
            __syncthreads();
            // ---- gate fuse + state update: thread -> (seqU, cols gcol..gcol+1)
            float hn0, hn1, cn0, cn1;
            {
                float i0 = g_s[(0 * 8 + seqU) * 64 + j0]     + us2f((u16)(px[d][0] & 0xffffu));
                float i1 = g_s[(0 * 8 + seqU) * 64 + j0 + 1] + us2f((u16)(px[d][0] >> 16));
                float f0 = g_s[(1 * 8 + seqU) * 64 + j0]     + us2f((u16)(px[d][1] & 0xffffu));
                float f1 = g_s[(1 * 8 + seqU) * 64 + j0 + 1] + us2f((u16)(px[d][1] >> 16));
                float g0 = g_s[(2 * 8 + seqU) * 64 + j0]     + us2f((u16)(px[d][2] & 0xffffu));
                float g1 = g_s[(2 * 8 + seqU) * 64 + j0 + 1] + us2f((u16)(px[d][2] >> 16));
                float o0 = g_s[(3 * 8 + seqU) * 64 + j0]     + us2f((u16)(px[d][3] & 0xffffu));
                float o1 = g_s[(3 * 8 + seqU) * 64 + j0 + 1] + us2f((u16)(px[d][3] >> 16));
                float cA = c_s[d][seqU * 64 + j0], cB = c_s[d][seqU * 64 + j0 + 1];
                cn0 = sigm_f(f0) * cA + sigm_f(i0) * tanh_f(g0);
                cn1 = sigm_f(f1) * cB + sigm_f(i1) * tanh_f(g1);
                hn0 = sigm_f(o0) * tanh_f(cn0);
                hn1 = sigm_f(o1) * tanh_f(cn1);
                c_s[d][seqU * 64 + j0] = cn0;
                c_s[d][seqU * 64 + j0 + 1] = cn1;
                u32 hpack = (u32)f2us(hn0) | ((u32)f2us(hn1) << 16);
                __hip_atomic_store(hxg + d * 2048 + (t & 1) * 1024 + seqU * 128 + (gcol >> 1),
                                   hpack, __ATOMIC_RELAXED, __HIP_MEMORY_SCOPE_AGENT);
            }
            // drain own agent-scope hx stores, then signal
            asm volatile("s_waitcnt vmcnt(0)" ::: "memory");
            __syncthreads();
            if (tid == 0 && !last)
                __hip_atomic_store(&flg[d * 4 + s], (u32)(t + 1),
                                   __ATOMIC_RELEASE, __HIP_MEMORY_SCOPE_AGENT);
            // ---- deferred global outputs + next-step x prefetch (overlap)
            if (!lastOnly) {
                int wr = writeAtSource ? tt : t;
                float mk = (wr >= mylen) ? 0.f : 1.f;
                size_t ro = ((size_t)(bat * 8 + seqU)) * L + wr;
                u32 hp2 = (u32)f2us(hn0 * mk) | ((u32)f2us(hn1 * mk) << 16);
                *(u32*)(hOut + ro * hStride + d * RR + gcol) = hp2;
                if (cOut) {
                    u32 cp2 = (u32)f2us(cn0 * mk) | ((u32)f2us(cn1 * mk) << 16);
                    *(u32*)(cOut + ro * cStride + d * RR + gcol) = cp2;
                }
            } else if (last) {
                size_t ro = (size_t)(seqBase + bat * 8 + seqU);
                u32 hp2 = (u32)f2us(hn0) | ((u32)f2us(hn1) << 16);
                *(u32*)(hOut + ro * hStride + d * RR + gcol) = hp2;
            }
            if (!last) {
                const int tn = d ? (L - 2 - t) : (t + 1);
                const u16* xr = (d ? xWb : xWf) + (((size_t)(bat * 8 + seqU)) * L + tn) * G4 + gcol;
                px[d][0] = *(const u32*)xr;
                px[d][1] = *(const u32*)(xr + 256);
                px[d][2] = *(const u32*)(xr + 512);
                px[d][3] = *(const u32*)(xr + 768);
            }
        }
    }
}

// ------------------------- small fused kernels -----------------------------
__global__ void hprev_k(const u16* __restrict__ G, u16* __restrict__ Hp) {
    int idx = blockIdx.x * 256 + threadIdx.x;
    if (idx < BT * H2) {
        int r = idx >> 9, d = idx & 511;
        int t = r & (TT - 1);
        Hp[idx] = (t == 0) ? (u16)0 : G[(size_t)(r - 1) * G4 + d];
    }
}
__global__ void s_k(const float* __restrict__ e, const u16* __restrict__ mB,
                    u16* __restrict__ sB) {
    int i = blockIdx.x * 256 + threadIdx.x;
    if (i < BT * H2) sB[i] = f2us(sigm(e[i]) * tanhf(us2f(mB[i])));
}
__global__ void z_k(const float* __restrict__ cWh, const float* __restrict__ cWu,
                    const float* __restrict__ Wv, float* __restrict__ z) {
    int idx = blockIdx.x * 256 + threadIdx.x;
    if (idx >= BT * SS) return;
    int r = idx >> 5, s = idx & 31;
    int b = r >> 9;
    const float* ph = cWh + (size_t)r * MDU_;
    const float* pu = cWu + (size_t)(b * SS + s) * MDU_;
    float acc = 0.f;
    for (int j = 0; j < MDU_; ++j) acc += tanhf(ph[j] + pu[j]) * Wv[j];
    z[idx] = acc;
}
__global__ void zhat_k(const float* __restrict__ sW, const float* __restrict__ cWh,
                       const float* __restrict__ Wv, float* __restrict__ zhat) {
    int r = blockIdx.x * 256 + threadIdx.x;
    if (r >= BT) return;
    float acc = 0.f;
    const float* ps = sW + (size_t)r * MDU_;
    const float* ph = cWh + (size_t)r * MDU_;
    for (int j = 0; j < MDU_; ++j) acc += tanhf(ps[j] + ph[j]) * Wv[j];
    zhat[r] = acc;
}
__global__ __launch_bounds__(64)
void attn_mix_k(const float* __restrict__ z, const float* __restrict__ zhat,
                const u16* __restrict__ U, const u16* __restrict__ sB,
                u16* __restrict__ G) {
    int r = blockIdx.x;
    int lane = threadIdx.x;
    int b = r >> 9;
    __shared__ float alpha[SS];
    float zv = (lane < SS) ? z[(size_t)r * SS + lane] : -1e30f;
    float mx = zv;
    for (int o = 32; o > 0; o >>= 1) mx = fmaxf(mx, __shfl_xor(mx, o));
    float ez = (lane < SS) ? expf(zv - mx) : 0.f;
    float s1 = ez;
    for (int o = 32; o > 0; o >>= 1) s1 += __shfl_xor(s1, o);
    float zh = zhat[r];
    float mx2 = fmaxf(mx, zh);
    float denom = s1 * expf(mx - mx2) + expf(zh - mx2);
    float beta = expf(zh - mx2) / denom;
    if (lane < SS) alpha[lane] = ez / s1;
    __syncthreads();
    for (int d = lane; d < H2; d += 64) {
        float cv = 0.f;
#pragma unroll 8
        for (int s2 = 0; s2 < SS; ++s2)
            cv += alpha[s2] * us2f(U[(size_t)(b * SS + s2) * H2 + d]);
        float sv = us2f(sB[(size_t)r * H2 + d]);
        G[(size_t)r * G4 + H2 + d] = f2us(beta * sv + (1.f - beta) * cv);
    }
}
__global__ __launch_bounds__(256)
void logit_k(const u16* __restrict__ G, const u16* __restrict__ Mb,
             const u16* __restrict__ Wout, const float* __restrict__ boutF,
             void* __restrict__ out, const int* __restrict__ flag) {
    int r = blockIdx.x * 4 + (threadIdx.x >> 6);
    if (r >= BT) return;
    int lane = threadIdx.x & 63;
    float acc[TAGS_] = {0, 0, 0, 0, 0, 0, 0};
    for (int k = lane; k < 1536; k += 64) {
        float v = (k < G4) ? us2f(G[(size_t)r * G4 + k]) : us2f(Mb[(size_t)r * H2 + (k - G4)]);
#pragma unroll
        for (int tg = 0; tg < TAGS_; ++tg) acc[tg] += v * us2f(Wout[tg * 1536 + k]);
    }
#pragma unroll
    for (int tg = 0; tg < TAGS_; ++tg) {
        float s = acc[tg];
        for (int o = 32; o > 0; o >>= 1) s += __shfl_xor(s, o);
        acc[tg] = s;
    }
    if (lane == 0) {
        int bf = *flag;
#pragma unroll
        for (int tg = 0; tg < TAGS_; ++tg) {
            float v = acc[tg] + boutF[tg];
            if (bf) ((u16*)out)[(size_t)r * TAGS_ + tg] = f2us(v);
            else    ((float*)out)[(size_t)r * TAGS_ + tg] = v;
        }
    }
}

// ---------------------------------------------------------------------------
extern "C" void kernel_launch(void* const* d_in, const int* in_sizes, int n_in,
                              void* d_out, int out_size, void* d_ws, size_t ws_size,
                              hipStream_t stream)
{
    const void* x_text = d_in[0];
    const void* x_syn  = d_in[1];
    const int* len_ctx = (const int*)d_in[3];
    const void *Wih[6], *Whh[6], *bih[6], *bhh[6];
    for (int l = 0; l < 6; ++l) {
        Wih[l] = d_in[5 + l * 4 + 0];
        Whh[l] = d_in[5 + l * 4 + 1];
        bih[l] = d_in[5 + l * 4 + 2];
        bhh[l] = d_in[5 + l * 4 + 3];
    }
    const void* W_cWh = d_in[29];
    const void* W_cWu = d_in[30];
    const void* W_v   = d_in[31];
    const void* W_sWh = d_in[32];
    const void* W_sWu = d_in[33];
    const void* W_Ws  = d_in[34];
    const void* W_out = d_in[35];
    const void* b_out = d_in[36];
    (void)in_sizes; (void)n_in; (void)out_size;

    char* ws = (char*)d_ws;
    size_t off = 0;
    auto alloc = [&](size_t bytes) -> void* {
        void* p = ws + off;
        off += (bytes + 255) & ~(size_t)255;
        return p;
    };
    int*   flagB  = (int*)alloc(256);
    float* bsum[6];
    for (int l = 0; l < 6; ++l) bsum[l] = (float*)alloc((size_t)G4 * 4);
    u16*   WsumB  = (u16*)alloc((size_t)H2 * H2 * 2);
    u16*   Ub     = (u16*)alloc((size_t)NSEQ * H2 * 2);
    u16*   Gb     = (u16*)alloc((size_t)BT * G4 * 2);
    u16*   mMb    = (u16*)alloc((size_t)BT * H2 * 2);
    float* cWhB   = (float*)alloc((size_t)BT * MDU_ * 4);
    float* cWuB   = (float*)alloc((size_t)NSEQ * MDU_ * 4);
    float* sWB    = (float*)alloc((size_t)BT * MDU_ * 4);
    float* zB     = (float*)alloc((size_t)BT * SS * 4);
    float* zhatB  = (float*)alloc((size_t)BT * 4);
    u16*   Wcwh16 = (u16*)alloc((size_t)MDU_ * H2 * 2);
    u16*   Wcwu16 = (u16*)alloc((size_t)MDU_ * H2 * 2);
    u16*   Wws16  = (u16*)alloc((size_t)MDU_ * H2 * 2);
    u16*   Wout16 = (u16*)alloc((size_t)TAGS_ * 1536 * 2);
    float* WvF    = (float*)alloc((size_t)MDU_ * 4);
    float* boutF  = (float*)alloc((size_t)TAGS_ * 4);
    u16*   WF[6];
    for (int l = 0; l < 6; ++l) WF[l] = (u16*)alloc((size_t)G4 * RR * 2);   // 512KB each
    u32*   cnts   = (u32*)alloc((size_t)128 * 16 * 4);                      // per-(grp) flag lines
    u32*   hx32   = (u32*)alloc((size_t)128 * 4096 * 4);                    // 2MB h exchange

    // choose synopsis mode by remaining workspace
    size_t fixedEnd = off;
    bool bigws = (ws_size >= fixedEnd + (size_t)81 * MB1);
    char* BIG = (char*)alloc(bigws ? (size_t)80 * MB1 : (size_t)24 * MB1);

    // BIG overlays (phases B/C/D; fit within first 24MB)
    u16*   bufA  = (u16*)BIG;
    u16*   bufB  = (u16*)(BIG + (size_t)8 * MB1);
    u16*   x16   = (u16*)(BIG + (size_t)16 * MB1);
    u16*   W16a  = (u16*)(BIG + (size_t)19 * MB1 + MB1 / 2);
    u16*   W16b  = (u16*)(BIG + (size_t)20 * MB1 + MB1 / 2);
    u16*   HprevB = (u16*)BIG;
    float* eBuf   = (float*)(BIG + (size_t)4 * MB1);
    u16*   sBuf   = (u16*)(BIG + (size_t)12 * MB1);
    u16*   mxWf  = (u16*)BIG;
    u16*   mxWb  = (u16*)(BIG + (size_t)8 * MB1);
    u16*   W16aD = (u16*)(BIG + (size_t)16 * MB1);
    u16*   W16bD = (u16*)(BIG + (size_t)18 * MB1);
    // merged-synopsis overlays (only valid when bigws)
    u16*   mbufA = (u16*)BIG;                            // 32MB
    u16*   mbufB = (u16*)(BIG + (size_t)32 * MB1);       // 32MB
    u16*   mx16  = (u16*)(BIG + (size_t)64 * MB1);       // 13.1MB
    u16*   mW16a = (u16*)(BIG + (size_t)78 * MB1);
    u16*   mW16b = (u16*)(BIG + (size_t)79 * MB1);

    auto cgrid = [](long n) { return dim3((unsigned)((n + 255) / 256)); };

    // ---- prep ----
    detect_k<<<dim3(1), dim3(256), 0, stream>>>(x_text, flagB);
    zero_k<<<cgrid(128 * 16), dim3(256), 0, stream>>>(cnts, 128 * 16);
    castbf_k<<<cgrid(MDU_ * H2), dim3(256), 0, stream>>>(W_cWh, 0, Wcwh16, MDU_ * H2, flagB);
    castbf_k<<<cgrid(MDU_ * H2), dim3(256), 0, stream>>>(W_cWu, 0, Wcwu16, MDU_ * H2, flagB);
    castbf_k<<<cgrid(MDU_ * H2), dim3(256), 0, stream>>>(W_Ws, 0, Wws16, MDU_ * H2, flagB);
    castbf_k<<<cgrid(TAGS_ * 1536), dim3(256), 0, stream>>>(W_out, 0, Wout16, TAGS_ * 1536, flagB);
    castf_k<<<cgrid(MDU_), dim3(256), 0, stream>>>(W_v, WvF, MDU_, flagB);
    castf_k<<<cgrid(TAGS_), dim3(256), 0, stream>>>(b_out, boutF, TAGS_, flagB);
    for (int l = 0; l < 6; ++l) {
        bias_sum_k<<<dim3(4), dim3(256), 0, stream>>>(bih[l], bhh[l], bsum[l], flagB);
        whh_frag_k<<<dim3(1024), dim3(256), 0, stream>>>(Whh[l], WF[l], flagB);
    }
    wsum_k<<<cgrid(H2 * H2), dim3(256), 0, stream>>>(W_sWh, W_sWu, WsumB, flagB);

    // ---- phase A: synopsis -> U ----
    if (bigws) {
        // all 256 seqs in one pass: one gemm pair + ONE lstm dispatch (64 steps)
        castbf_k<<<cgrid(G4 * DD), dim3(256), 0, stream>>>(Wih[2], 0, mW16a, G4 * DD, flagB);
        castbf_k<<<cgrid(G4 * DD), dim3(256), 0, stream>>>(Wih[3], 0, mW16b, G4 * DD, flagB);
        castbf_k<<<cgrid((long)NSEQ * JJ * DD), dim3(256), 0, stream>>>(x_syn, 0, mx16, (long)NSEQ * JJ * DD, flagB);
        gemm_bt<<<dim3(8, (NSEQ * JJ) / BM), dim3(256), 0, stream>>>(mx16, DD, mW16a, DD, mbufA, G4, bsum[2], NSEQ * JJ, G4, DD, 1);
        gemm_bt<<<dim3(8, (NSEQ * JJ) / BM), dim3(256), 0, stream>>>(mx16, DD, mW16b, DD, mbufB, G4, bsum[3], NSEQ * JJ, G4, DD, 1);
        lstm_coop<<<dim3(4, 32), dim3(256), 0, stream>>>(
            mbufA, mbufB, WF[2], WF[3], JJ,
            Ub, H2, (u16*)nullptr, 0, (const int*)nullptr,
            0, 1, 0, hx32, cnts, 2);
    } else {
        castbf_k<<<cgrid(G4 * DD), dim3(256), 0, stream>>>(Wih[2], 0, W16a, G4 * DD, flagB);
        castbf_k<<<cgrid(G4 * DD), dim3(256), 0, stream>>>(Wih[3], 0, W16b, G4 * DD, flagB);
        for (int c = 0; c < NSEQ / SCH; ++c) {
            long chunkElems = (long)SCH * JJ * DD;
            castbf_k<<<cgrid(chunkElems), dim3(256), 0, stream>>>(x_syn, (long)c * chunkElems, x16, chunkElems, flagB);
            gemm_bt<<<dim3(8, (SCH * JJ) / BM), dim3(256), 0, stream>>>(x16, DD, W16a, DD, bufA, G4, bsum[2], SCH * JJ, G4, DD, 1);
            gemm_bt<<<dim3(8, (SCH * JJ) / BM), dim3(256), 0, stream>>>(x16, DD, W16b, DD, bufB, G4, bsum[3], SCH * JJ, G4, DD, 1);
            lstm_coop<<<dim3(4, 8), dim3(256), 0, stream>>>(
                bufA, bufB, WF[2], WF[3], JJ,
                Ub, H2, (u16*)nullptr, 0, (const int*)nullptr,
                0, 1, c * SCH, hx32, cnts, 2 + c * 8);
        }
    }

    // ---- phase B: context layer-1 -> H (Gb left), m (mMb) ----
    castbf_k<<<cgrid((long)BT * DD), dim3(256), 0, stream>>>(x_text, 0, x16, (long)BT * DD, flagB);
    castbf_k<<<cgrid(G4 * DD), dim3(256), 0, stream>>>(Wih[0], 0, W16a, G4 * DD, flagB);
    castbf_k<<<cgrid(G4 * DD), dim3(256), 0, stream>>>(Wih[1], 0, W16b, G4 * DD, flagB);
    gemm_bt<<<dim3(8, 32), dim3(256), 0, stream>>>(x16, DD, W16a, DD, bufA, G4, bsum[0], BT, G4, DD, 1);
    gemm_bt<<<dim3(8, 32), dim3(256), 0, stream>>>(x16, DD, W16b, DD, bufB, G4, bsum[1], BT, G4, DD, 1);
    lstm_coop<<<dim3(4, 1), dim3(256), 0, stream>>>(
        bufA, bufB, WF[0], WF[1], TT,
        Gb, G4, mMb, H2, len_ctx, 0, 0, 0, hx32, cnts, 0);

    // ---- phase C: attention ----
    gemm_bt<<<dim3(1, 32), dim3(256), 0, stream>>>(Gb, G4, Wcwh16, H2, cWhB, MDU_, nullptr, BT, MDU_, H2, 0);
    gemm_bt<<<dim3(1, 2),  dim3(256), 0, stream>>>(Ub, H2, Wcwu16, H2, cWuB, MDU_, nullptr, NSEQ, MDU_, H2, 0);
    hprev_k<<<cgrid(BT * H2), dim3(256), 0, stream>>>(Gb, HprevB);
    gemm_bt<<<dim3(4, 32), dim3(256), 0, stream>>>(HprevB, H2, WsumB, H2, eBuf, H2, nullptr, BT, H2, H2, 0);
    s_k<<<cgrid(BT * H2), dim3(256), 0, stream>>>(eBuf, mMb, sBuf);
    gemm_bt<<<dim3(1, 32), dim3(256), 0, stream>>>(sBuf, H2, Wws16, H2, sWB, MDU_, nullptr, BT, MDU_, H2, 0);
    z_k<<<cgrid(BT * SS), dim3(256), 0, stream>>>(cWhB, cWuB, WvF, zB);
    zhat_k<<<cgrid(BT), dim3(256), 0, stream>>>(sWB, cWhB, WvF, zhatB);
    attn_mix_k<<<dim3(BT), dim3(64), 0, stream>>>(zB, zhatB, Ub, sBuf, Gb);

    // ---- phase D: layer-2 LSTMs over G -> M (into mMb) ----
    castbf_k<<<cgrid(G4 * G4), dim3(256), 0, stream>>>(Wih[4], 0, W16aD, G4 * G4, flagB);
    castbf_k<<<cgrid(G4 * G4), dim3(256), 0, stream>>>(Wih[5], 0, W16bD, G4 * G4, flagB);
    gemm_bt<<<dim3(8, 32), dim3(256), 0, stream>>>(Gb, G4, W16aD, G4, mxWf, G4, bsum[4], BT, G4, G4, 1);
    gemm_bt<<<dim3(8, 32), dim3(256), 0, stream>>>(Gb, G4, W16bD, G4, mxWb, G4, bsum[5], BT, G4, G4, 1);
    lstm_coop<<<dim3(4, 1), dim3(256), 0, stream>>>(
        mxWf, mxWb, WF[4], WF[5], TT,
        mMb, H2, (u16*)nullptr, 0, (const int*)nullptr, 1, 0, 0, hx32, cnts, 1);

    // ---- output ----
    logit_k<<<dim3(BT / 4), dim3(256), 0, stream>>>(Gb, mMb, Wout16, boutF, d_out, flagB);
}

// Round 5
// 4931.762 us; speedup vs baseline: 1.5936x; 1.5936x over previous
//
#include <hip/hip_runtime.h>
#include <math.h>
#include <stddef.h>

// ---------------------------------------------------------------------------
// ATT_SYN: bi-LSTM encoder + synopsis attention + 2nd bi-LSTM + tag head.
// B=8 T=512 S=32 J=64 D=400 R=256 MDU=100 TAGS=7
// Recurrence: cooperative 4-WG-per-direction kernel, Whh resident in VGPRs
// (128/lane), per-step device-scope flag sync. Round-5 = verified round-2
// structure + safe fixes:
//   - disjoint flag/hx group lines per dispatch (fixes round-2 latent B/D
//     collision; round-4's unverifiable L2 fast path is withdrawn)
//   - all-lane relaxed poll + agent acquire fence (round-3-validated),
//     removing one RT + one barrier per step vs round 2
//   - c-state in registers (owned exclusively per update thread)
// ---------------------------------------------------------------------------

#define BB 8
#define TT 512
#define SS 32
#define JJ 64
#define DD 400
#define RR 256
#define G4 1024
#define H2 512
#define MDU_ 100
#define TAGS_ 7
#define BT (BB*TT)
#define NSEQ (BB*SS)
#define SCH 64
#define MB1 (1024*1024)

typedef __attribute__((ext_vector_type(8))) short short8;
typedef __attribute__((ext_vector_type(4))) float floatx4;
typedef __attribute__((ext_vector_type(4))) unsigned int u32x4;
typedef unsigned short u16;
typedef unsigned int u32;

__device__ __forceinline__ float us2f(u16 u) {
    unsigned int v = ((unsigned int)u) << 16;
    return __builtin_bit_cast(float, v);
}
__device__ __forceinline__ u16 f2us(float f) {
    unsigned int v = __builtin_bit_cast(unsigned int, f);
    v += 0x7FFFu + ((v >> 16) & 1u);
    return (u16)(v >> 16);
}
__device__ __forceinline__ float ldin(const void* p, long i, int bf) {
    return bf ? us2f(((const u16*)p)[i]) : ((const float*)p)[i];
}
__device__ __forceinline__ float sigm(float x) { return 1.0f / (1.0f + expf(-x)); }
// fast activations for the recurrence critical path (NaN-safe)
__device__ __forceinline__ float sigm_f(float x) { return 1.0f / (1.0f + __expf(-x)); }
__device__ __forceinline__ float tanh_f(float x) {
    float e = __expf(-2.0f * fabsf(x));
    float t = (1.0f - e) / (1.0f + e);
    return copysignf(t, x);
}

// ---- dtype probe ----
__global__ void detect_k(const void* x, int* flag) {
    __shared__ int cnt;
    if (threadIdx.x == 0) cnt = 0;
    __syncthreads();
    u16 lo = ((const u16*)x)[threadIdx.x * 2];
    int e = (lo >> 7) & 0xFF;
    if (e >= 118 && e <= 131) atomicAdd(&cnt, 1);
    __syncthreads();
    if (threadIdx.x == 0) *flag = (cnt > 128) ? 1 : 0;
}
__global__ void castbf_k(const void* src, long off, u16* dst, long n, const int* flag) {
    long i = (long)blockIdx.x * 256 + threadIdx.x;
    if (i < n) dst[i] = (*flag) ? ((const u16*)src)[off + i] : f2us(((const float*)src)[off + i]);
}
__global__ void castf_k(const void* src, float* dst, long n, const int* flag) {
    long i = (long)blockIdx.x * 256 + threadIdx.x;
    if (i < n) dst[i] = ldin(src, i, *flag);
}
__global__ void zero_k(u32* p, long n) {
    long i = (long)blockIdx.x * 256 + threadIdx.x;
    if (i < n) p[i] = 0u;
}
__global__ void bias_sum_k(const void* bih, const void* bhh, float* out, const int* flag) {
    int i = blockIdx.x * 256 + threadIdx.x;
    if (i < G4) out[i] = ldin(bih, i, *flag) + ldin(bhh, i, *flag);
}
__global__ void wsum_k(const void* a, const void* b, u16* o, const int* flag) {
    int i = blockIdx.x * 256 + threadIdx.x;
    if (i < H2 * H2) o[i] = f2us(ldin(a, i, *flag) + ldin(b, i, *flag));
}
// Whh [1024,256] -> pre-swizzled MFMA B-fragments (4-slice partition):
// WF[((((s*4+w)*4+t)*8+c)*64+lane)*8+j] = Whh[(w*256+s*64+t*16+(lane&15))*256
//                                              + c*32+(lane>>4)*8+j]
__global__ void whh_frag_k(const void* Whh, u16* WF, const int* flag) {
    int i = blockIdx.x * 256 + threadIdx.x;
    if (i >= 4 * 4 * 4 * 8 * 64 * 8) return;
    int j  = i & 7;
    int ln = (i >> 3) & 63;
    int c  = (i >> 9) & 7;
    int t  = (i >> 12) & 3;
    int w  = (i >> 14) & 3;
    int s  = (i >> 16) & 3;
    int n_g = w * 256 + s * 64 + t * 16 + (ln & 15);
    int k   = c * 32 + (ln >> 4) * 8 + j;
    WF[i] = f2us(ldin(Whh, (long)n_g * 256 + k, *flag));
}

// ---------------------------------------------------------------------------
// GEMM: C[M,N] = A[M,K] @ W[N,K]^T (+bias); A,W bf16; C f32 or bf16.
// ---------------------------------------------------------------------------
#define BM 128
#define BN 128
#define BK 32
#define LDT 40

__global__ __launch_bounds__(256)
void gemm_bt(const u16* __restrict__ A, int lda,
             const u16* __restrict__ W, int ldw,
             void* __restrict__ C, int ldc,
             const float* __restrict__ bias,
             int M, int N, int K, int outBf16)
{
    __shared__ alignas(16) short As[BM * LDT];
    __shared__ alignas(16) short Bs[BN * LDT];
    const int tid  = threadIdx.x;
    const int m0   = blockIdx.y * BM;
    const int n0   = blockIdx.x * BN;
    const int lane = tid & 63;
    const int wave = tid >> 6;
    const int wm   = wave >> 1, wn = wave & 1;
    const int quad = lane >> 4, mrow = lane & 15;

    floatx4 acc[4][4];
#pragma unroll
    for (int i = 0; i < 4; ++i)
#pragma unroll
        for (int j = 0; j < 4; ++j) { floatx4 z4 = {0.f,0.f,0.f,0.f}; acc[i][j] = z4; }

    for (int k0 = 0; k0 < K; k0 += BK) {
#pragma unroll
        for (int cc = 0; cc < 2; ++cc) {
            int c   = tid + cc * 256;
            int row = c >> 2;
            int kc  = (c & 3) << 3;
            int gk  = k0 + kc;
            {
                int gr = m0 + row;
                short8 v;
                if (gr < M && gk + 8 <= K) {
                    v = *(const short8*)(A + (size_t)gr * lda + gk);
                } else {
#pragma unroll
                    for (int e = 0; e < 8; ++e)
                        v[e] = (gr < M && (gk + e) < K) ? (short)A[(size_t)gr * lda + gk + e] : (short)0;
                }
                *(short8*)&As[row * LDT + kc] = v;
            }
            {
                int gn = n0 + row;
                short8 v;
                if (gn < N && gk + 8 <= K) {
                    v = *(const short8*)(W + (size_t)gn * ldw + gk);
                } else {
#pragma unroll
                    for (int e = 0; e < 8; ++e)
                        v[e] = (gn < N && (gk + e) < K) ? (short)W[(size_t)gn * ldw + gk + e] : (short)0;
                }
                *(short8*)&Bs[row * LDT + kc] = v;
            }
        }
        __syncthreads();

        short8 af[4], bf[4];
#pragma unroll
        for (int i = 0; i < 4; ++i)
            af[i] = *(const short8*)&As[(wm * 64 + i * 16 + mrow) * LDT + quad * 8];
#pragma unroll
        for (int j = 0; j < 4; ++j)
            bf[j] = *(const short8*)&Bs[(wn * 64 + j * 16 + mrow) * LDT + quad * 8];
#pragma unroll
        for (int i = 0; i < 4; ++i)
#pragma unroll
            for (int j = 0; j < 4; ++j)
                acc[i][j] = __builtin_amdgcn_mfma_f32_16x16x32_bf16(af[i], bf[j], acc[i][j], 0, 0, 0);
        __syncthreads();
    }

#pragma unroll
    for (int i = 0; i < 4; ++i)
#pragma unroll
        for (int j = 0; j < 4; ++j)
#pragma unroll
            for (int r = 0; r < 4; ++r) {
                int row = m0 + wm * 64 + i * 16 + quad * 4 + r;
                int col = n0 + wn * 64 + j * 16 + mrow;
                if (row < M && col < N) {
                    float v = acc[i][j][r];
                    if (bias) v += bias[col];
                    if (outBf16) ((u16*)C)[(size_t)row * ldc + col] = f2us(v);
                    else         ((float*)C)[(size_t)row * ldc + col] = v;
                }
            }
}

// ---------------------------------------------------------------------------
// Cooperative LSTM: grid (4 slices, 2 dirs, nbatch). Group = (dir,batch) of 4
// slice-WGs; each WG: 256 thr (4 waves), wave w = gate type, 64x256 bf16 Whh
// slice resident in 128 VGPRs. M=8 seqs/WG. Per-step sync: per-WG flag slot
// (store-release own after drain+barrier; all-lane relaxed poll of all 4 +
// agent acquire fence — no extra RT, no trailing barrier). Deferred output
// stores + x prefetch overlap the spin. c-state lives in registers.
// ---------------------------------------------------------------------------
__global__ __launch_bounds__(256, 1)
void lstm_coop(const u16* __restrict__ xWf, const u16* __restrict__ xWb,
               const u16* __restrict__ WFf, const u16* __restrict__ WFb,
               int L,
               u16* __restrict__ hOut, int hStride,
               u16* __restrict__ cOut, int cStride,
               const int* __restrict__ lenp,
               int writeAtSource, int lastOnly, int seqBase,
               u32* __restrict__ hx32, u32* __restrict__ flags, int grpBase)
{
    const int s   = blockIdx.x;        // slice (owns gate cols s*64..s*64+63)
    const int dir = blockIdx.y;
    const int bat = blockIdx.z;
    const int nb  = gridDim.z;
    const int tid = threadIdx.x;
    const int wv  = tid >> 6;          // gate type i,f,g,o
    const int ln  = tid & 63;
    const int q   = ln >> 4, m = ln & 15;
    const u16* xW = dir ? xWb : xWf;
    const u16* WF = dir ? WFb : WFf;
    const int grp = grpBase + dir * nb + bat;
    u32* flg = flags + (size_t)grp * 16;    // slots [0..3] = per-WG step flags
    u32* hx  = hx32 + (size_t)grp * 2048;   // [2 parity][8 seq][128 u32]

    __shared__ float g_s[4 * 8 * 64];

    // resident B fragments: 4 N-tiles x 8 K-chunks, 16B/lane each = 128 VGPRs
    short8 bw[4][8];
    {
        const u16* wb = WF + ((size_t)(s * 4 + wv) * 32) * 512 + ln * 8;
#pragma unroll
        for (int t4 = 0; t4 < 4; ++t4)
#pragma unroll
            for (int c = 0; c < 8; ++c)
                bw[t4][c] = *(const short8*)(wb + (size_t)(t4 * 8 + c) * 512);
    }

    const int seqU = tid >> 5;             // update phase: seq 0..7
    const int j0   = (tid & 31) * 2;       // local col pair within slice
    const int gcol = s * 64 + j0;          // global gate col
    const int mylen = lenp ? lenp[bat * 8 + seqU] : 0x7fffffff;
    float cR0 = 0.f, cR1 = 0.f;            // c-state: exclusively this thread's

    // preload x gate values for t=0
    u32 px0, px1, px2, px3;
    {
        const int tt0 = dir ? (L - 1) : 0;
        const u16* xr = xW + (((size_t)(bat * 8 + seqU)) * L + tt0) * G4 + gcol;
        px0 = *(const u32*)xr;
        px1 = *(const u32*)(xr + 256);
        px2 = *(const u32*)(xr + 512);
        px3 = *(const u32*)(xr + 768);
    }

    for (int t = 0; t < L; ++t) {
        const int tt = dir ? (L - 1 - t) : t;
        // ---- A fragments from hx[(t-1)&1]
        short8 a[8];
        if (t > 0) {
            const u32* hp = hx + ((t - 1) & 1) * 1024 + m * 128;
#pragma unroll
            for (int c = 0; c < 8; ++c) {
                if (m < 8) {
                    u32x4 v = *(const u32x4*)(hp + c * 16 + q * 4);
                    a[c] = __builtin_bit_cast(short8, v);
                } else {
                    short8 z = {0,0,0,0,0,0,0,0}; a[c] = z;
                }
            }
        } else {
            short8 z = {0,0,0,0,0,0,0,0};
#pragma unroll
            for (int c = 0; c < 8; ++c) a[c] = z;
        }
        floatx4 acc[4];
#pragma unroll
        for (int t4 = 0; t4 < 4; ++t4) { floatx4 z4 = {0.f,0.f,0.f,0.f}; acc[t4] = z4; }
#pragma unroll
        for (int c = 0; c < 8; ++c)
#pragma unroll
            for (int t4 = 0; t4 < 4; ++t4)
                acc[t4] = __builtin_amdgcn_mfma_f32_16x16x32_bf16(a[c], bw[t4][c], acc[t4], 0, 0, 0);
        // C layout: seq = q*4+r (valid q<2), col n = t4*16 + m
        if (q < 2) {
#pragma unroll
            for (int t4 = 0; t4 < 4; ++t4)
#pragma unroll
                for (int r = 0; r < 4; ++r)
                    g_s[(wv * 8 + q * 4 + r) * 64 + t4 * 16 + m] = acc[t4][r];
        }
        __syncthreads();
        // ---- gate fuse + state update: thread -> (seqU, cols gcol..gcol+1)
        float hn0, hn1, cn0, cn1;
        {
            float i0 = g_s[(0 * 8 + seqU) * 64 + j0]     + us2f((u16)(px0 & 0xffffu));
            float i1 = g_s[(0 * 8 + seqU) * 64 + j0 + 1] + us2f((u16)(px0 >> 16));
            float f0 = g_s[(1 * 8 + seqU) * 64 + j0]     + us2f((u16)(px1 & 0xffffu));
            float f1 = g_s[(1 * 8 + seqU) * 64 + j0 + 1] + us2f((u16)(px1 >> 16));
            float g0 = g_s[(2 * 8 + seqU) * 64 + j0]     + us2f((u16)(px2 & 0xffffu));
            float g1 = g_s[(2 * 8 + seqU) * 64 + j0 + 1] + us2f((u16)(px2 >> 16));
            float o0 = g_s[(3 * 8 + seqU) * 64 + j0]     + us2f((u16)(px3 & 0xffffu));
            float o1 = g_s[(3 * 8 + seqU) * 64 + j0 + 1] + us2f((u16)(px3 >> 16));
            cn0 = sigm_f(f0) * cR0 + sigm_f(i0) * tanh_f(g0);
            cn1 = sigm_f(f1) * cR1 + sigm_f(i1) * tanh_f(g1);
            hn0 = sigm_f(o0) * tanh_f(cn0);
            hn1 = sigm_f(o1) * tanh_f(cn1);
            cR0 = cn0;
            cR1 = cn1;
            u32 hpack = (u32)f2us(hn0) | ((u32)f2us(hn1) << 16);
            __hip_atomic_store(hx + (t & 1) * 1024 + seqU * 128 + (gcol >> 1),
                               hpack, __ATOMIC_RELAXED, __HIP_MEMORY_SCOPE_AGENT);
        }
        // drain own agent-scope hx store, then barrier, then signal
        asm volatile("s_waitcnt vmcnt(0)" ::: "memory");
        __syncthreads();
        const bool last = (t == L - 1);
        if (tid == 0 && !last)
            __hip_atomic_store(&flg[s], (u32)(t + 1),
                               __ATOMIC_RELEASE, __HIP_MEMORY_SCOPE_AGENT);
        // ---- deferred global outputs: overlap the spin ----
        if (!lastOnly) {
            int wr = writeAtSource ? tt : t;
            float mk = (wr >= mylen) ? 0.f : 1.f;
            size_t ro = ((size_t)(bat * 8 + seqU)) * L + wr;
            u32 hp2 = (u32)f2us(hn0 * mk) | ((u32)f2us(hn1 * mk) << 16);
            *(u32*)(hOut + ro * hStride + dir * RR + gcol) = hp2;
            if (cOut) {
                u32 cp2 = (u32)f2us(cn0 * mk) | ((u32)f2us(cn1 * mk) << 16);
                *(u32*)(cOut + ro * cStride + dir * RR + gcol) = cp2;
            }
        } else if (last) {
            size_t ro = (size_t)(seqBase + bat * 8 + seqU);
            u32 hp2 = (u32)f2us(hn0) | ((u32)f2us(hn1) << 16);
            *(u32*)(hOut + ro * hStride + dir * RR + gcol) = hp2;
        }
        if (!last) {
            // prefetch next-step x gate values (in flight during the spin)
            {
                const int tn = dir ? (L - 2 - t) : (t + 1);
                const u16* xr = xW + (((size_t)(bat * 8 + seqU)) * L + tn) * G4 + gcol;
                px0 = *(const u32*)xr;
                px1 = *(const u32*)(xr + 256);
                px2 = *(const u32*)(xr + 512);
                px3 = *(const u32*)(xr + 768);
            }
            // all-lane relaxed poll; exit requires own WG's flag (set after
            // the post-drain barrier), so no trailing __syncthreads needed.
            // Acquire FENCE after the poll synchronizes-with the release
            // stores (fence-atomic rule) and invalidates L1 for hx reloads.
            const u32 tgt = (u32)(t + 1);
            long guard = 0;
            for (;;) {
                u32 f0 = __hip_atomic_load(&flg[0], __ATOMIC_RELAXED, __HIP_MEMORY_SCOPE_AGENT);
                u32 f1 = __hip_atomic_load(&flg[1], __ATOMIC_RELAXED, __HIP_MEMORY_SCOPE_AGENT);
                u32 f2 = __hip_atomic_load(&flg[2], __ATOMIC_RELAXED, __HIP_MEMORY_SCOPE_AGENT);
                u32 f3 = __hip_atomic_load(&flg[3], __ATOMIC_RELAXED, __HIP_MEMORY_SCOPE_AGENT);
                if (f0 >= tgt && f1 >= tgt && f2 >= tgt && f3 >= tgt) break;
                if (++guard > (1L << 18)) break;   // diagnostic bail
                if (guard > 16) __builtin_amdgcn_s_sleep(1);
            }
            __builtin_amdgcn_fence(__ATOMIC_ACQUIRE, "agent");
        }
    }
}

// ------------------------- small fused kernels -----------------------------
__global__ void hprev_k(const u16* __restrict__ G, u16* __restrict__ Hp) {
    int idx = blockIdx.x * 256 + threadIdx.x;
    if (idx < BT * H2) {
        int r = idx >> 9, d = idx & 511;
        int t = r & (TT - 1);
        Hp[idx] = (t == 0) ? (u16)0 : G[(size_t)(r - 1) * G4 + d];
    }
}
__global__ void s_k(const float* __restrict__ e, const u16* __restrict__ mB,
                    u16* __restrict__ sB) {
    int i = blockIdx.x * 256 + threadIdx.x;
    if (i < BT * H2) sB[i] = f2us(sigm(e[i]) * tanhf(us2f(mB[i])));
}
__global__ void z_k(const float* __restrict__ cWh, const float* __restrict__ cWu,
                    const float* __restrict__ Wv, float* __restrict__ z) {
    int idx = blockIdx.x * 256 + threadIdx.x;
    if (idx >= BT * SS) return;
    int r = idx >> 5, s = idx & 31;
    int b = r >> 9;
    const float* ph = cWh + (size_t)r * MDU_;
    const float* pu = cWu + (size_t)(b * SS + s) * MDU_;
    float acc = 0.f;
    for (int j = 0; j < MDU_; ++j) acc += tanhf(ph[j] + pu[j]) * Wv[j];
    z[idx] = acc;
}
__global__ void zhat_k(const float* __restrict__ sW, const float* __restrict__ cWh,
                       const float* __restrict__ Wv, float* __restrict__ zhat) {
    int r = blockIdx.x * 256 + threadIdx.x;
    if (r >= BT) return;
    float acc = 0.f;
    const float* ps = sW + (size_t)r * MDU_;
    const float* ph = cWh + (size_t)r * MDU_;
    for (int j = 0; j < MDU_; ++j) acc += tanhf(ps[j] + ph[j]) * Wv[j];
    zhat[r] = acc;
}
__global__ __launch_bounds__(64)
void attn_mix_k(const float* __restrict__ z, const float* __restrict__ zhat,
                const u16* __restrict__ U, const u16* __restrict__ sB,
                u16* __restrict__ G) {
    int r = blockIdx.x;
    int lane = threadIdx.x;
    int b = r >> 9;
    __shared__ float alpha[SS];
    float zv = (lane < SS) ? z[(size_t)r * SS + lane] : -1e30f;
    float mx = zv;
    for (int o = 32; o > 0; o >>= 1) mx = fmaxf(mx, __shfl_xor(mx, o));
    float ez = (lane < SS) ? expf(zv - mx) : 0.f;
    float s1 = ez;
    for (int o = 32; o > 0; o >>= 1) s1 += __shfl_xor(s1, o);
    float zh = zhat[r];
    float mx2 = fmaxf(mx, zh);
    float denom = s1 * expf(mx - mx2) + expf(zh - mx2);
    float beta = expf(zh - mx2) / denom;
    if (lane < SS) alpha[lane] = ez / s1;
    __syncthreads();
    for (int d = lane; d < H2; d += 64) {
        float cv = 0.f;
#pragma unroll 8
        for (int s2 = 0; s2 < SS; ++s2)
            cv += alpha[s2] * us2f(U[(size_t)(b * SS + s2) * H2 + d]);
        float sv = us2f(sB[(size_t)r * H2 + d]);
        G[(size_t)r * G4 + H2 + d] = f2us(beta * sv + (1.f - beta) * cv);
    }
}
__global__ __launch_bounds__(256)
void logit_k(const u16* __restrict__ G, const u16* __restrict__ Mb,
             const u16* __restrict__ Wout, const float* __restrict__ boutF,
             void* __restrict__ out, const int* __restrict__ flag) {
    int r = blockIdx.x * 4 + (threadIdx.x >> 6);
    if (r >= BT) return;
    int lane = threadIdx.x & 63;
    float acc[TAGS_] = {0, 0, 0, 0, 0, 0, 0};
    for (int k = lane; k < 1536; k += 64) {
        float v = (k < G4) ? us2f(G[(size_t)r * G4 + k]) : us2f(Mb[(size_t)r * H2 + (k - G4)]);
#pragma unroll
        for (int tg = 0; tg < TAGS_; ++tg) acc[tg] += v * us2f(Wout[tg * 1536 + k]);
    }
#pragma unroll
    for (int tg = 0; tg < TAGS_; ++tg) {
        float s = acc[tg];
        for (int o = 32; o > 0; o >>= 1) s += __shfl_xor(s, o);
        acc[tg] = s;
    }
    if (lane == 0) {
        int bf = *flag;
#pragma unroll
        for (int tg = 0; tg < TAGS_; ++tg) {
            float v = acc[tg] + boutF[tg];
            if (bf) ((u16*)out)[(size_t)r * TAGS_ + tg] = f2us(v);
            else    ((float*)out)[(size_t)r * TAGS_ + tg] = v;
        }
    }
}

// ---------------------------------------------------------------------------
extern "C" void kernel_launch(void* const* d_in, const int* in_sizes, int n_in,
                              void* d_out, int out_size, void* d_ws, size_t ws_size,
                              hipStream_t stream)
{
    const void* x_text = d_in[0];
    const void* x_syn  = d_in[1];
    const int* len_ctx = (const int*)d_in[3];
    const void *Wih[6], *Whh[6], *bih[6], *bhh[6];
    for (int l = 0; l < 6; ++l) {
        Wih[l] = d_in[5 + l * 4 + 0];
        Whh[l] = d_in[5 + l * 4 + 1];
        bih[l] = d_in[5 + l * 4 + 2];
        bhh[l] = d_in[5 + l * 4 + 3];
    }
    const void* W_cWh = d_in[29];
    const void* W_cWu = d_in[30];
    const void* W_v   = d_in[31];
    const void* W_sWh = d_in[32];
    const void* W_sWu = d_in[33];
    const void* W_Ws  = d_in[34];
    const void* W_out = d_in[35];
    const void* b_out = d_in[36];
    (void)in_sizes; (void)n_in; (void)out_size;

    char* ws = (char*)d_ws;
    size_t off = 0;
    auto alloc = [&](size_t bytes) -> void* {
        void* p = ws + off;
        off += (bytes + 255) & ~(size_t)255;
        return p;
    };
    int*   flagB  = (int*)alloc(256);
    float* bsum[6];
    for (int l = 0; l < 6; ++l) bsum[l] = (float*)alloc((size_t)G4 * 4);
    u16*   WsumB  = (u16*)alloc((size_t)H2 * H2 * 2);
    u16*   Ub     = (u16*)alloc((size_t)NSEQ * H2 * 2);
    u16*   Gb     = (u16*)alloc((size_t)BT * G4 * 2);
    u16*   mMb    = (u16*)alloc((size_t)BT * H2 * 2);
    float* cWhB   = (float*)alloc((size_t)BT * MDU_ * 4);
    float* cWuB   = (float*)alloc((size_t)NSEQ * MDU_ * 4);
    float* sWB    = (float*)alloc((size_t)BT * MDU_ * 4);
    float* zB     = (float*)alloc((size_t)BT * SS * 4);
    float* zhatB  = (float*)alloc((size_t)BT * 4);
    u16*   Wcwh16 = (u16*)alloc((size_t)MDU_ * H2 * 2);
    u16*   Wcwu16 = (u16*)alloc((size_t)MDU_ * H2 * 2);
    u16*   Wws16  = (u16*)alloc((size_t)MDU_ * H2 * 2);
    u16*   Wout16 = (u16*)alloc((size_t)TAGS_ * 1536 * 2);
    float* WvF    = (float*)alloc((size_t)MDU_ * 4);
    float* boutF  = (float*)alloc((size_t)TAGS_ * 4);
    u16*   WF[6];
    for (int l = 0; l < 6; ++l) WF[l] = (u16*)alloc((size_t)G4 * RR * 2);   // 512KB each
    u32*   cnts   = (u32*)alloc((size_t)128 * 16 * 4);                      // per-WG flag lines
    u32*   hx32   = (u32*)alloc((size_t)128 * 2048 * 4);                    // 1MB h exchange

    // choose synopsis mode by remaining workspace
    size_t fixedEnd = off;
    bool bigws = (ws_size >= fixedEnd + (size_t)81 * MB1);
    char* BIG = (char*)alloc(bigws ? (size_t)80 * MB1 : (size_t)24 * MB1);

    // BIG overlays (phases B/C/D; fit within first 24MB)
    u16*   bufA  = (u16*)BIG;
    u16*   bufB  = (u16*)(BIG + (size_t)8 * MB1);
    u16*   x16   = (u16*)(BIG + (size_t)16 * MB1);
    u16*   W16a  = (u16*)(BIG + (size_t)19 * MB1 + MB1 / 2);
    u16*   W16b  = (u16*)(BIG + (size_t)20 * MB1 + MB1 / 2);
    u16*   HprevB = (u16*)BIG;
    float* eBuf   = (float*)(BIG + (size_t)4 * MB1);
    u16*   sBuf   = (u16*)(BIG + (size_t)12 * MB1);
    u16*   mxWf  = (u16*)BIG;
    u16*   mxWb  = (u16*)(BIG + (size_t)8 * MB1);
    u16*   W16aD = (u16*)(BIG + (size_t)16 * MB1);
    u16*   W16bD = (u16*)(BIG + (size_t)18 * MB1);
    // merged-synopsis overlays (only valid when bigws)
    u16*   mbufA = (u16*)BIG;                            // 32MB
    u16*   mbufB = (u16*)(BIG + (size_t)32 * MB1);       // 32MB
    u16*   mx16  = (u16*)(BIG + (size_t)64 * MB1);       // 13.1MB
    u16*   mW16a = (u16*)(BIG + (size_t)78 * MB1);
    u16*   mW16b = (u16*)(BIG + (size_t)79 * MB1);

    auto cgrid = [](long n) { return dim3((unsigned)((n + 255) / 256)); };

    // ---- prep ----
    detect_k<<<dim3(1), dim3(256), 0, stream>>>(x_text, flagB);
    zero_k<<<cgrid(128 * 16), dim3(256), 0, stream>>>(cnts, 128 * 16);
    castbf_k<<<cgrid(MDU_ * H2), dim3(256), 0, stream>>>(W_cWh, 0, Wcwh16, MDU_ * H2, flagB);
    castbf_k<<<cgrid(MDU_ * H2), dim3(256), 0, stream>>>(W_cWu, 0, Wcwu16, MDU_ * H2, flagB);
    castbf_k<<<cgrid(MDU_ * H2), dim3(256), 0, stream>>>(W_Ws, 0, Wws16, MDU_ * H2, flagB);
    castbf_k<<<cgrid(TAGS_ * 1536), dim3(256), 0, stream>>>(W_out, 0, Wout16, TAGS_ * 1536, flagB);
    castf_k<<<cgrid(MDU_), dim3(256), 0, stream>>>(W_v, WvF, MDU_, flagB);
    castf_k<<<cgrid(TAGS_), dim3(256), 0, stream>>>(b_out, boutF, TAGS_, flagB);
    for (int l = 0; l < 6; ++l) {
        bias_sum_k<<<dim3(4), dim3(256), 0, stream>>>(bih[l], bhh[l], bsum[l], flagB);
        whh_frag_k<<<dim3(1024), dim3(256), 0, stream>>>(Whh[l], WF[l], flagB);
    }
    wsum_k<<<cgrid(H2 * H2), dim3(256), 0, stream>>>(W_sWh, W_sWu, WsumB, flagB);

    // ---- phase A: synopsis -> U ----  (groups 4..67)
    if (bigws) {
        // all 256 seqs in one pass: one gemm pair + ONE lstm dispatch (64 steps)
        castbf_k<<<cgrid(G4 * DD), dim3(256), 0, stream>>>(Wih[2], 0, mW16a, G4 * DD, flagB);
        castbf_k<<<cgrid(G4 * DD), dim3(256), 0, stream>>>(Wih[3], 0, mW16b, G4 * DD, flagB);
        castbf_k<<<cgrid((long)NSEQ * JJ * DD), dim3(256), 0, stream>>>(x_syn, 0, mx16, (long)NSEQ * JJ * DD, flagB);
        gemm_bt<<<dim3(8, (NSEQ * JJ) / BM), dim3(256), 0, stream>>>(mx16, DD, mW16a, DD, mbufA, G4, bsum[2], NSEQ * JJ, G4, DD, 1);
        gemm_bt<<<dim3(8, (NSEQ * JJ) / BM), dim3(256), 0, stream>>>(mx16, DD, mW16b, DD, mbufB, G4, bsum[3], NSEQ * JJ, G4, DD, 1);
        lstm_coop<<<dim3(4, 2, 32), dim3(256), 0, stream>>>(
            mbufA, mbufB, WF[2], WF[3], JJ,
            Ub, H2, (u16*)nullptr, 0, (const int*)nullptr,
            0, 1, 0, hx32, cnts, 4);
    } else {
        castbf_k<<<cgrid(G4 * DD), dim3(256), 0, stream>>>(Wih[2], 0, W16a, G4 * DD, flagB);
        castbf_k<<<cgrid(G4 * DD), dim3(256), 0, stream>>>(Wih[3], 0, W16b, G4 * DD, flagB);
        for (int c = 0; c < NSEQ / SCH; ++c) {
            long chunkElems = (long)SCH * JJ * DD;
            castbf_k<<<cgrid(chunkElems), dim3(256), 0, stream>>>(x_syn, (long)c * chunkElems, x16, chunkElems, flagB);
            gemm_bt<<<dim3(8, (SCH * JJ) / BM), dim3(256), 0, stream>>>(x16, DD, W16a, DD, bufA, G4, bsum[2], SCH * JJ, G4, DD, 1);
            gemm_bt<<<dim3(8, (SCH * JJ) / BM), dim3(256), 0, stream>>>(x16, DD, W16b, DD, bufB, G4, bsum[3], SCH * JJ, G4, DD, 1);
            lstm_coop<<<dim3(4, 2, 8), dim3(256), 0, stream>>>(
                bufA, bufB, WF[2], WF[3], JJ,
                Ub, H2, (u16*)nullptr, 0, (const int*)nullptr,
                0, 1, c * SCH, hx32, cnts, 4 + c * 16);
        }
    }

    // ---- phase B: context layer-1 -> H (Gb left), m (mMb) ----  (groups 0,1)
    castbf_k<<<cgrid((long)BT * DD), dim3(256), 0, stream>>>(x_text, 0, x16, (long)BT * DD, flagB);
    castbf_k<<<cgrid(G4 * DD), dim3(256), 0, stream>>>(Wih[0], 0, W16a, G4 * DD, flagB);
    castbf_k<<<cgrid(G4 * DD), dim3(256), 0, stream>>>(Wih[1], 0, W16b, G4 * DD, flagB);
    gemm_bt<<<dim3(8, 32), dim3(256), 0, stream>>>(x16, DD, W16a, DD, bufA, G4, bsum[0], BT, G4, DD, 1);
    gemm_bt<<<dim3(8, 32), dim3(256), 0, stream>>>(x16, DD, W16b, DD, bufB, G4, bsum[1], BT, G4, DD, 1);
    lstm_coop<<<dim3(4, 2, 1), dim3(256), 0, stream>>>(
        bufA, bufB, WF[0], WF[1], TT,
        Gb, G4, mMb, H2, len_ctx, 0, 0, 0, hx32, cnts, 0);

    // ---- phase C: attention ----
    gemm_bt<<<dim3(1, 32), dim3(256), 0, stream>>>(Gb, G4, Wcwh16, H2, cWhB, MDU_, nullptr, BT, MDU_, H2, 0);
    gemm_bt<<<dim3(1, 2),  dim3(256), 0, stream>>>(Ub, H2, Wcwu16, H2, cWuB, MDU_, nullptr, NSEQ, MDU_, H2, 0);
    hprev_k<<<cgrid(BT * H2), dim3(256), 0, stream>>>(Gb, HprevB);
    gemm_bt<<<dim3(4, 32), dim3(256), 0, stream>>>(HprevB, H2, WsumB, H2, eBuf, H2, nullptr, BT, H2, H2, 0);
    s_k<<<cgrid(BT * H2), dim3(256), 0, stream>>>(eBuf, mMb, sBuf);
    gemm_bt<<<dim3(1, 32), dim3(256), 0, stream>>>(sBuf, H2, Wws16, H2, sWB, MDU_, nullptr, BT, MDU_, H2, 0);
    z_k<<<cgrid(BT * SS), dim3(256), 0, stream>>>(cWhB, cWuB, WvF, zB);
    zhat_k<<<cgrid(BT), dim3(256), 0, stream>>>(sWB, cWhB, WvF, zhatB);
    attn_mix_k<<<dim3(BT), dim3(64), 0, stream>>>(zB, zhatB, Ub, sBuf, Gb);

    // ---- phase D: layer-2 LSTMs over G -> M (into mMb) ----  (groups 2,3)
    castbf_k<<<cgrid(G4 * G4), dim3(256), 0, stream>>>(Wih[4], 0, W16aD, G4 * G4, flagB);
    castbf_k<<<cgrid(G4 * G4), dim3(256), 0, stream>>>(Wih[5], 0, W16bD, G4 * G4, flagB);
    gemm_bt<<<dim3(8, 32), dim3(256), 0, stream>>>(Gb, G4, W16aD, G4, mxWf, G4, bsum[4], BT, G4, G4, 1);
    gemm_bt<<<dim3(8, 32), dim3(256), 0, stream>>>(Gb, G4, W16bD, G4, mxWb, G4, bsum[5], BT, G4, G4, 1);
    lstm_coop<<<dim3(4, 2, 1), dim3(256), 0, stream>>>(
        mxWf, mxWb, WF[4], WF[5], TT,
        mMb, H2, (u16*)nullptr, 0, (const int*)nullptr, 1, 0, 0, hx32, cnts, 2);

    // ---- output ----
    logit_k<<<dim3(BT / 4), dim3(256), 0, stream>>>(Gb, mMb, Wout16, boutF, d_out, flagB);
}

// Round 6
// 4183.223 us; speedup vs baseline: 1.8787x; 1.1789x over previous
//
#include <hip/hip_runtime.h>
#include <math.h>
#include <stddef.h>

// ---------------------------------------------------------------------------
// ATT_SYN: bi-LSTM encoder + synopsis attention + 2nd bi-LSTM + tag head.
// B=8 T=512 S=32 J=64 D=400 R=256 MDU=100 TAGS=7
// Recurrence: cooperative 4-WG-per-direction kernel, Whh resident in VGPRs
// (128/lane), per-step device-scope flag sync. Round-6:
//   - tid0-only relaxed poll (round-2-verified; round-5's all-lane poll
//     created read-storm contention at the coherence point: 1600->1790us)
//   - poll exit via tid0 acquire FENCE + __syncthreads (saves round-2's
//     extra acquire-load RT; same physical L1-invalidate mechanism)
//   - per-flag 64B lines (producers' release stores no longer fight for
//     one line's ownership)
//   - XCD-packed flat grid (members share wgid mod 8 -> same XCD under
//     round-robin dispatch; pure remap, no memory-model change)
//   - disjoint group lines, c-state in regs, deferred stores + x prefetch
// ---------------------------------------------------------------------------

#define BB 8
#define TT 512
#define SS 32
#define JJ 64
#define DD 400
#define RR 256
#define G4 1024
#define H2 512
#define MDU_ 100
#define TAGS_ 7
#define BT (BB*TT)
#define NSEQ (BB*SS)
#define SCH 64
#define MB1 (1024*1024)

typedef __attribute__((ext_vector_type(8))) short short8;
typedef __attribute__((ext_vector_type(4))) float floatx4;
typedef __attribute__((ext_vector_type(4))) unsigned int u32x4;
typedef unsigned short u16;
typedef unsigned int u32;

__device__ __forceinline__ float us2f(u16 u) {
    unsigned int v = ((unsigned int)u) << 16;
    return __builtin_bit_cast(float, v);
}
__device__ __forceinline__ u16 f2us(float f) {
    unsigned int v = __builtin_bit_cast(unsigned int, f);
    v += 0x7FFFu + ((v >> 16) & 1u);
    return (u16)(v >> 16);
}
__device__ __forceinline__ float ldin(const void* p, long i, int bf) {
    return bf ? us2f(((const u16*)p)[i]) : ((const float*)p)[i];
}
__device__ __forceinline__ float sigm(float x) { return 1.0f / (1.0f + expf(-x)); }
// fast activations for the recurrence critical path (NaN-safe)
__device__ __forceinline__ float sigm_f(float x) { return 1.0f / (1.0f + __expf(-x)); }
__device__ __forceinline__ float tanh_f(float x) {
    float e = __expf(-2.0f * fabsf(x));
    float t = (1.0f - e) / (1.0f + e);
    return copysignf(t, x);
}

// ---- dtype probe ----
__global__ void detect_k(const void* x, int* flag) {
    __shared__ int cnt;
    if (threadIdx.x == 0) cnt = 0;
    __syncthreads();
    u16 lo = ((const u16*)x)[threadIdx.x * 2];
    int e = (lo >> 7) & 0xFF;
    if (e >= 118 && e <= 131) atomicAdd(&cnt, 1);
    __syncthreads();
    if (threadIdx.x == 0) *flag = (cnt > 128) ? 1 : 0;
}
__global__ void castbf_k(const void* src, long off, u16* dst, long n, const int* flag) {
    long i = (long)blockIdx.x * 256 + threadIdx.x;
    if (i < n) dst[i] = (*flag) ? ((const u16*)src)[off + i] : f2us(((const float*)src)[off + i]);
}
__global__ void castf_k(const void* src, float* dst, long n, const int* flag) {
    long i = (long)blockIdx.x * 256 + threadIdx.x;
    if (i < n) dst[i] = ldin(src, i, *flag);
}
__global__ void zero_k(u32* p, long n) {
    long i = (long)blockIdx.x * 256 + threadIdx.x;
    if (i < n) p[i] = 0u;
}
__global__ void bias_sum_k(const void* bih, const void* bhh, float* out, const int* flag) {
    int i = blockIdx.x * 256 + threadIdx.x;
    if (i < G4) out[i] = ldin(bih, i, *flag) + ldin(bhh, i, *flag);
}
__global__ void wsum_k(const void* a, const void* b, u16* o, const int* flag) {
    int i = blockIdx.x * 256 + threadIdx.x;
    if (i < H2 * H2) o[i] = f2us(ldin(a, i, *flag) + ldin(b, i, *flag));
}
// Whh [1024,256] -> pre-swizzled MFMA B-fragments (4-slice partition):
// WF[((((s*4+w)*4+t)*8+c)*64+lane)*8+j] = Whh[(w*256+s*64+t*16+(lane&15))*256
//                                              + c*32+(lane>>4)*8+j]
__global__ void whh_frag_k(const void* Whh, u16* WF, const int* flag) {
    int i = blockIdx.x * 256 + threadIdx.x;
    if (i >= 4 * 4 * 4 * 8 * 64 * 8) return;
    int j  = i & 7;
    int ln = (i >> 3) & 63;
    int c  = (i >> 9) & 7;
    int t  = (i >> 12) & 3;
    int w  = (i >> 14) & 3;
    int s  = (i >> 16) & 3;
    int n_g = w * 256 + s * 64 + t * 16 + (ln & 15);
    int k   = c * 32 + (ln >> 4) * 8 + j;
    WF[i] = f2us(ldin(Whh, (long)n_g * 256 + k, *flag));
}

// ---------------------------------------------------------------------------
// GEMM: C[M,N] = A[M,K] @ W[N,K]^T (+bias); A,W bf16; C f32 or bf16.
// ---------------------------------------------------------------------------
#define BM 128
#define BN 128
#define BK 32
#define LDT 40

__global__ __launch_bounds__(256)
void gemm_bt(const u16* __restrict__ A, int lda,
             const u16* __restrict__ W, int ldw,
             void* __restrict__ C, int ldc,
             const float* __restrict__ bias,
             int M, int N, int K, int outBf16)
{
    __shared__ alignas(16) short As[BM * LDT];
    __shared__ alignas(16) short Bs[BN * LDT];
    const int tid  = threadIdx.x;
    const int m0   = blockIdx.y * BM;
    const int n0   = blockIdx.x * BN;
    const int lane = tid & 63;
    const int wave = tid >> 6;
    const int wm   = wave >> 1, wn = wave & 1;
    const int quad = lane >> 4, mrow = lane & 15;

    floatx4 acc[4][4];
#pragma unroll
    for (int i = 0; i < 4; ++i)
#pragma unroll
        for (int j = 0; j < 4; ++j) { floatx4 z4 = {0.f,0.f,0.f,0.f}; acc[i][j] = z4; }

    for (int k0 = 0; k0 < K; k0 += BK) {
#pragma unroll
        for (int cc = 0; cc < 2; ++cc) {
            int c   = tid + cc * 256;
            int row = c >> 2;
            int kc  = (c & 3) << 3;
            int gk  = k0 + kc;
            {
                int gr = m0 + row;
                short8 v;
                if (gr < M && gk + 8 <= K) {
                    v = *(const short8*)(A + (size_t)gr * lda + gk);
                } else {
#pragma unroll
                    for (int e = 0; e < 8; ++e)
                        v[e] = (gr < M && (gk + e) < K) ? (short)A[(size_t)gr * lda + gk + e] : (short)0;
                }
                *(short8*)&As[row * LDT + kc] = v;
            }
            {
                int gn = n0 + row;
                short8 v;
                if (gn < N && gk + 8 <= K) {
                    v = *(const short8*)(W + (size_t)gn * ldw + gk);
                } else {
#pragma unroll
                    for (int e = 0; e < 8; ++e)
                        v[e] = (gn < N && (gk + e) < K) ? (short)W[(size_t)gn * ldw + gk + e] : (short)0;
                }
                *(short8*)&Bs[row * LDT + kc] = v;
            }
        }
        __syncthreads();

        short8 af[4], bf[4];
#pragma unroll
        for (int i = 0; i < 4; ++i)
            af[i] = *(const short8*)&As[(wm * 64 + i * 16 + mrow) * LDT + quad * 8];
#pragma unroll
        for (int j = 0; j < 4; ++j)
            bf[j] = *(const short8*)&Bs[(wn * 64 + j * 16 + mrow) * LDT + quad * 8];
#pragma unroll
        for (int i = 0; i < 4; ++i)
#pragma unroll
            for (int j = 0; j < 4; ++j)
                acc[i][j] = __builtin_amdgcn_mfma_f32_16x16x32_bf16(af[i], bf[j], acc[i][j], 0, 0, 0);
        __syncthreads();
    }

#pragma unroll
    for (int i = 0; i < 4; ++i)
#pragma unroll
        for (int j = 0; j < 4; ++j)
#pragma unroll
            for (int r = 0; r < 4; ++r) {
                int row = m0 + wm * 64 + i * 16 + quad * 4 + r;
                int col = n0 + wn * 64 + j * 16 + mrow;
                if (row < M && col < N) {
                    float v = acc[i][j][r];
                    if (bias) v += bias[col];
                    if (outBf16) ((u16*)C)[(size_t)row * ldc + col] = f2us(v);
                    else         ((float*)C)[(size_t)row * ldc + col] = v;
                }
            }
}

// ---------------------------------------------------------------------------
// Cooperative LSTM. Flat grid of 4*G8 WGs: member s = wgid/G8 (slice),
// g = wgid%G8 (group = dir*nb+bat, active if g < 2*nb). G8 % 8 == 0 so a
// group's 4 members share wgid mod 8 -> same XCD under round-robin dispatch
// (performance heuristic only; correctness never depends on placement).
// Each WG: 256 thr (4 waves), wave w = gate type, 64x256 bf16 Whh slice
// resident in 128 VGPRs. M=8 seqs/group. Per-step sync: per-WG flag on its
// OWN 64B line (store-release after drain+barrier); tid0-only relaxed poll,
// exit via acquire fence + __syncthreads. Deferred output stores + x
// prefetch overlap the spin. c-state lives in registers.
// ---------------------------------------------------------------------------
__global__ __launch_bounds__(256, 1)
void lstm_coop(const u16* __restrict__ xWf, const u16* __restrict__ xWb,
               const u16* __restrict__ WFf, const u16* __restrict__ WFb,
               int L,
               u16* __restrict__ hOut, int hStride,
               u16* __restrict__ cOut, int cStride,
               const int* __restrict__ lenp,
               int writeAtSource, int lastOnly, int seqBase,
               u32* __restrict__ hx32, u32* __restrict__ flags,
               int grpBase, int nb, int G8)
{
    const int wgid = blockIdx.x;
    const int s    = wgid / G8;          // slice (gate cols s*64..s*64+63)
    const int g    = wgid - s * G8;      // group id
    if (g >= 2 * nb) return;
    const int dir  = g / nb;
    const int bat  = g - dir * nb;
    const int tid = threadIdx.x;
    const int wv  = tid >> 6;            // gate type i,f,g,o
    const int ln  = tid & 63;
    const int q   = ln >> 4, m = ln & 15;
    const u16* xW = dir ? xWb : xWf;
    const u16* WF = dir ? WFb : WFf;
    const int grp = grpBase + g;
    u32* flg = flags + (size_t)grp * 64;    // 4 slots, one 64B line each
    u32* hx  = hx32 + (size_t)grp * 2048;   // [2 parity][8 seq][128 u32]

    __shared__ float g_s[4 * 8 * 64];

    // resident B fragments: 4 N-tiles x 8 K-chunks, 16B/lane each = 128 VGPRs
    short8 bw[4][8];
    {
        const u16* wb = WF + ((size_t)(s * 4 + wv) * 32) * 512 + ln * 8;
#pragma unroll
        for (int t4 = 0; t4 < 4; ++t4)
#pragma unroll
            for (int c = 0; c < 8; ++c)
                bw[t4][c] = *(const short8*)(wb + (size_t)(t4 * 8 + c) * 512);
    }

    const int seqU = tid >> 5;             // update phase: seq 0..7
    const int j0   = (tid & 31) * 2;       // local col pair within slice
    const int gcol = s * 64 + j0;          // global gate col
    const int mylen = lenp ? lenp[bat * 8 + seqU] : 0x7fffffff;
    float cR0 = 0.f, cR1 = 0.f;            // c-state: exclusively this thread's

    // preload x gate values for t=0
    u32 px0, px1, px2, px3;
    {
        const int tt0 = dir ? (L - 1) : 0;
        const u16* xr = xW + (((size_t)(bat * 8 + seqU)) * L + tt0) * G4 + gcol;
        px0 = *(const u32*)xr;
        px1 = *(const u32*)(xr + 256);
        px2 = *(const u32*)(xr + 512);
        px3 = *(const u32*)(xr + 768);
    }

    for (int t = 0; t < L; ++t) {
        const int tt = dir ? (L - 1 - t) : t;
        // ---- A fragments from hx[(t-1)&1]
        short8 a[8];
        if (t > 0) {
            const u32* hp = hx + ((t - 1) & 1) * 1024 + m * 128;
#pragma unroll
            for (int c = 0; c < 8; ++c) {
                if (m < 8) {
                    u32x4 v = *(const u32x4*)(hp + c * 16 + q * 4);
                    a[c] = __builtin_bit_cast(short8, v);
                } else {
                    short8 z = {0,0,0,0,0,0,0,0}; a[c] = z;
                }
            }
        } else {
            short8 z = {0,0,0,0,0,0,0,0};
#pragma unroll
            for (int c = 0; c < 8; ++c) a[c] = z;
        }
        floatx4 acc[4];
#pragma unroll
        for (int t4 = 0; t4 < 4; ++t4) { floatx4 z4 = {0.f,0.f,0.f,0.f}; acc[t4] = z4; }
#pragma unroll
        for (int c = 0; c < 8; ++c)
#pragma unroll
            for (int t4 = 0; t4 < 4; ++t4)
                acc[t4] = __builtin_amdgcn_mfma_f32_16x16x32_bf16(a[c], bw[t4][c], acc[t4], 0, 0, 0);
        // C layout: seq = q*4+r (valid q<2), col n = t4*16 + m
        if (q < 2) {
#pragma unroll
            for (int t4 = 0; t4 < 4; ++t4)
#pragma unroll
                for (int r = 0; r < 4; ++r)
                    g_s[(wv * 8 + q * 4 + r) * 64 + t4 * 16 + m] = acc[t4][r];
        }
        __syncthreads();
        // ---- gate fuse + state update: thread -> (seqU, cols gcol..gcol+1)
        float hn0, hn1, cn0, cn1;
        {
            float i0 = g_s[(0 * 8 + seqU) * 64 + j0]     + us2f((u16)(px0 & 0xffffu));
            float i1 = g_s[(0 * 8 + seqU) * 64 + j0 + 1] + us2f((u16)(px0 >> 16));
            float f0 = g_s[(1 * 8 + seqU) * 64 + j0]     + us2f((u16)(px1 & 0xffffu));
            float f1 = g_s[(1 * 8 + seqU) * 64 + j0 + 1] + us2f((u16)(px1 >> 16));
            float g0 = g_s[(2 * 8 + seqU) * 64 + j0]     + us2f((u16)(px2 & 0xffffu));
            float g1 = g_s[(2 * 8 + seqU) * 64 + j0 + 1] + us2f((u16)(px2 >> 16));
            float o0 = g_s[(3 * 8 + seqU) * 64 + j0]     + us2f((u16)(px3 & 0xffffu));
            float o1 = g_s[(3 * 8 + seqU) * 64 + j0 + 1] + us2f((u16)(px3 >> 16));
            cn0 = sigm_f(f0) * cR0 + sigm_f(i0) * tanh_f(g0);
            cn1 = sigm_f(f1) * cR1 + sigm_f(i1) * tanh_f(g1);
            hn0 = sigm_f(o0) * tanh_f(cn0);
            hn1 = sigm_f(o1) * tanh_f(cn1);
            cR0 = cn0;
            cR1 = cn1;
            u32 hpack = (u32)f2us(hn0) | ((u32)f2us(hn1) << 16);
            __hip_atomic_store(hx + (t & 1) * 1024 + seqU * 128 + (gcol >> 1),
                               hpack, __ATOMIC_RELAXED, __HIP_MEMORY_SCOPE_AGENT);
        }
        // drain own agent-scope hx store, then barrier, then signal
        asm volatile("s_waitcnt vmcnt(0)" ::: "memory");
        __syncthreads();
        const bool last = (t == L - 1);
        if (tid == 0 && !last)
            __hip_atomic_store(&flg[s * 16], (u32)(t + 1),
                               __ATOMIC_RELEASE, __HIP_MEMORY_SCOPE_AGENT);
        // ---- deferred global outputs: overlap the spin ----
        if (!lastOnly) {
            int wr = writeAtSource ? tt : t;
            float mk = (wr >= mylen) ? 0.f : 1.f;
            size_t ro = ((size_t)(bat * 8 + seqU)) * L + wr;
            u32 hp2 = (u32)f2us(hn0 * mk) | ((u32)f2us(hn1 * mk) << 16);
            *(u32*)(hOut + ro * hStride + dir * RR + gcol) = hp2;
            if (cOut) {
                u32 cp2 = (u32)f2us(cn0 * mk) | ((u32)f2us(cn1 * mk) << 16);
                *(u32*)(cOut + ro * cStride + dir * RR + gcol) = cp2;
            }
        } else if (last) {
            size_t ro = (size_t)(seqBase + bat * 8 + seqU);
            u32 hp2 = (u32)f2us(hn0) | ((u32)f2us(hn1) << 16);
            *(u32*)(hOut + ro * hStride + dir * RR + gcol) = hp2;
        }
        if (!last) {
            // prefetch next-step x gate values (in flight during the spin)
            {
                const int tn = dir ? (L - 2 - t) : (t + 1);
                const u16* xr = xW + (((size_t)(bat * 8 + seqU)) * L + tn) * G4 + gcol;
                px0 = *(const u32*)xr;
                px1 = *(const u32*)(xr + 256);
                px2 = *(const u32*)(xr + 512);
                px3 = *(const u32*)(xr + 768);
            }
            // tid0-only relaxed poll (minimal coherence-point traffic);
            // acquire FENCE on exit invalidates this CU's L1 so all waves'
            // hx reloads (after the barrier) fetch fresh lines — same
            // mechanism round 2 verified via its acquire load, minus one RT.
            if (tid == 0) {
                const u32 tgt = (u32)(t + 1);
                long guard = 0;
                for (;;) {
                    u32 f0 = __hip_atomic_load(&flg[0],  __ATOMIC_RELAXED, __HIP_MEMORY_SCOPE_AGENT);
                    u32 f1 = __hip_atomic_load(&flg[16], __ATOMIC_RELAXED, __HIP_MEMORY_SCOPE_AGENT);
                    u32 f2 = __hip_atomic_load(&flg[32], __ATOMIC_RELAXED, __HIP_MEMORY_SCOPE_AGENT);
                    u32 f3 = __hip_atomic_load(&flg[48], __ATOMIC_RELAXED, __HIP_MEMORY_SCOPE_AGENT);
                    if (f0 >= tgt && f1 >= tgt && f2 >= tgt && f3 >= tgt) break;
                    if (++guard > (1L << 18)) break;   // diagnostic bail
                    if (guard > 32) __builtin_amdgcn_s_sleep(1);
                }
                __builtin_amdgcn_fence(__ATOMIC_ACQUIRE, "agent");
            }
            __syncthreads();
        }
    }
}

// ------------------------- small fused kernels -----------------------------
__global__ void hprev_k(const u16* __restrict__ G, u16* __restrict__ Hp) {
    int idx = blockIdx.x * 256 + threadIdx.x;
    if (idx < BT * H2) {
        int r = idx >> 9, d = idx & 511;
        int t = r & (TT - 1);
        Hp[idx] = (t == 0) ? (u16)0 : G[(size_t)(r - 1) * G4 + d];
    }
}
__global__ void s_k(const float* __restrict__ e, const u16* __restrict__ mB,
                    u16* __restrict__ sB) {
    int i = blockIdx.x * 256 + threadIdx.x;
    if (i < BT * H2) sB[i] = f2us(sigm(e[i]) * tanhf(us2f(mB[i])));
}
__global__ void z_k(const float* __restrict__ cWh, const float* __restrict__ cWu,
                    const float* __restrict__ Wv, float* __restrict__ z) {
    int idx = blockIdx.x * 256 + threadIdx.x;
    if (idx >= BT * SS) return;
    int r = idx >> 5, s = idx & 31;
    int b = r >> 9;
    const float* ph = cWh + (size_t)r * MDU_;
    const float* pu = cWu + (size_t)(b * SS + s) * MDU_;
    float acc = 0.f;
    for (int j = 0; j < MDU_; ++j) acc += tanhf(ph[j] + pu[j]) * Wv[j];
    z[idx] = acc;
}
__global__ void zhat_k(const float* __restrict__ sW, const float* __restrict__ cWh,
                       const float* __restrict__ Wv, float* __restrict__ zhat) {
    int r = blockIdx.x * 256 + threadIdx.x;
    if (r >= BT) return;
    float acc = 0.f;
    const float* ps = sW + (size_t)r * MDU_;
    const float* ph = cWh + (size_t)r * MDU_;
    for (int j = 0; j < MDU_; ++j) acc += tanhf(ps[j] + ph[j]) * Wv[j];
    zhat[r] = acc;
}
__global__ __launch_bounds__(64)
void attn_mix_k(const float* __restrict__ z, const float* __restrict__ zhat,
                const u16* __restrict__ U, const u16* __restrict__ sB,
                u16* __restrict__ G) {
    int r = blockIdx.x;
    int lane = threadIdx.x;
    int b = r >> 9;
    __shared__ float alpha[SS];
    float zv = (lane < SS) ? z[(size_t)r * SS + lane] : -1e30f;
    float mx = zv;
    for (int o = 32; o > 0; o >>= 1) mx = fmaxf(mx, __shfl_xor(mx, o));
    float ez = (lane < SS) ? expf(zv - mx) : 0.f;
    float s1 = ez;
    for (int o = 32; o > 0; o >>= 1) s1 += __shfl_xor(s1, o);
    float zh = zhat[r];
    float mx2 = fmaxf(mx, zh);
    float denom = s1 * expf(mx - mx2) + expf(zh - mx2);
    float beta = expf(zh - mx2) / denom;
    if (lane < SS) alpha[lane] = ez / s1;
    __syncthreads();
    for (int d = lane; d < H2; d += 64) {
        float cv = 0.f;
#pragma unroll 8
        for (int s2 = 0; s2 < SS; ++s2)
            cv += alpha[s2] * us2f(U[(size_t)(b * SS + s2) * H2 + d]);
        float sv = us2f(sB[(size_t)r * H2 + d]);
        G[(size_t)r * G4 + H2 + d] = f2us(beta * sv + (1.f - beta) * cv);
    }
}
__global__ __launch_bounds__(256)
void logit_k(const u16* __restrict__ G, const u16* __restrict__ Mb,
             const u16* __restrict__ Wout, const float* __restrict__ boutF,
             void* __restrict__ out, const int* __restrict__ flag) {
    int r = blockIdx.x * 4 + (threadIdx.x >> 6);
    if (r >= BT) return;
    int lane = threadIdx.x & 63;
    float acc[TAGS_] = {0, 0, 0, 0, 0, 0, 0};
    for (int k = lane; k < 1536; k += 64) {
        float v = (k < G4) ? us2f(G[(size_t)r * G4 + k]) : us2f(Mb[(size_t)r * H2 + (k - G4)]);
#pragma unroll
        for (int tg = 0; tg < TAGS_; ++tg) acc[tg] += v * us2f(Wout[tg * 1536 + k]);
    }
#pragma unroll
    for (int tg = 0; tg < TAGS_; ++tg) {
        float s = acc[tg];
        for (int o = 32; o > 0; o >>= 1) s += __shfl_xor(s, o);
        acc[tg] = s;
    }
    if (lane == 0) {
        int bf = *flag;
#pragma unroll
        for (int tg = 0; tg < TAGS_; ++tg) {
            float v = acc[tg] + boutF[tg];
            if (bf) ((u16*)out)[(size_t)r * TAGS_ + tg] = f2us(v);
            else    ((float*)out)[(size_t)r * TAGS_ + tg] = v;
        }
    }
}

// ---------------------------------------------------------------------------
extern "C" void kernel_launch(void* const* d_in, const int* in_sizes, int n_in,
                              void* d_out, int out_size, void* d_ws, size_t ws_size,
                              hipStream_t stream)
{
    const void* x_text = d_in[0];
    const void* x_syn  = d_in[1];
    const int* len_ctx = (const int*)d_in[3];
    const void *Wih[6], *Whh[6], *bih[6], *bhh[6];
    for (int l = 0; l < 6; ++l) {
        Wih[l] = d_in[5 + l * 4 + 0];
        Whh[l] = d_in[5 + l * 4 + 1];
        bih[l] = d_in[5 + l * 4 + 2];
        bhh[l] = d_in[5 + l * 4 + 3];
    }
    const void* W_cWh = d_in[29];
    const void* W_cWu = d_in[30];
    const void* W_v   = d_in[31];
    const void* W_sWh = d_in[32];
    const void* W_sWu = d_in[33];
    const void* W_Ws  = d_in[34];
    const void* W_out = d_in[35];
    const void* b_out = d_in[36];
    (void)in_sizes; (void)n_in; (void)out_size;

    char* ws = (char*)d_ws;
    size_t off = 0;
    auto alloc = [&](size_t bytes) -> void* {
        void* p = ws + off;
        off += (bytes + 255) & ~(size_t)255;
        return p;
    };
    int*   flagB  = (int*)alloc(256);
    float* bsum[6];
    for (int l = 0; l < 6; ++l) bsum[l] = (float*)alloc((size_t)G4 * 4);
    u16*   WsumB  = (u16*)alloc((size_t)H2 * H2 * 2);
    u16*   Ub     = (u16*)alloc((size_t)NSEQ * H2 * 2);
    u16*   Gb     = (u16*)alloc((size_t)BT * G4 * 2);
    u16*   mMb    = (u16*)alloc((size_t)BT * H2 * 2);
    float* cWhB   = (float*)alloc((size_t)BT * MDU_ * 4);
    float* cWuB   = (float*)alloc((size_t)NSEQ * MDU_ * 4);
    float* sWB    = (float*)alloc((size_t)BT * MDU_ * 4);
    float* zB     = (float*)alloc((size_t)BT * SS * 4);
    float* zhatB  = (float*)alloc((size_t)BT * 4);
    u16*   Wcwh16 = (u16*)alloc((size_t)MDU_ * H2 * 2);
    u16*   Wcwu16 = (u16*)alloc((size_t)MDU_ * H2 * 2);
    u16*   Wws16  = (u16*)alloc((size_t)MDU_ * H2 * 2);
    u16*   Wout16 = (u16*)alloc((size_t)TAGS_ * 1536 * 2);
    float* WvF    = (float*)alloc((size_t)MDU_ * 4);
    float* boutF  = (float*)alloc((size_t)TAGS_ * 4);
    u16*   WF[6];
    for (int l = 0; l < 6; ++l) WF[l] = (u16*)alloc((size_t)G4 * RR * 2);   // 512KB each
    u32*   cnts   = (u32*)alloc((size_t)128 * 64 * 4);                      // per-WG flags, 64B lines
    u32*   hx32   = (u32*)alloc((size_t)128 * 2048 * 4);                    // 1MB h exchange

    // choose synopsis mode by remaining workspace
    size_t fixedEnd = off;
    bool bigws = (ws_size >= fixedEnd + (size_t)81 * MB1);
    char* BIG = (char*)alloc(bigws ? (size_t)80 * MB1 : (size_t)24 * MB1);

    // BIG overlays (phases B/C/D; fit within first 24MB)
    u16*   bufA  = (u16*)BIG;
    u16*   bufB  = (u16*)(BIG + (size_t)8 * MB1);
    u16*   x16   = (u16*)(BIG + (size_t)16 * MB1);
    u16*   W16a  = (u16*)(BIG + (size_t)19 * MB1 + MB1 / 2);
    u16*   W16b  = (u16*)(BIG + (size_t)20 * MB1 + MB1 / 2);
    u16*   HprevB = (u16*)BIG;
    float* eBuf   = (float*)(BIG + (size_t)4 * MB1);
    u16*   sBuf   = (u16*)(BIG + (size_t)12 * MB1);
    u16*   mxWf  = (u16*)BIG;
    u16*   mxWb  = (u16*)(BIG + (size_t)8 * MB1);
    u16*   W16aD = (u16*)(BIG + (size_t)16 * MB1);
    u16*   W16bD = (u16*)(BIG + (size_t)18 * MB1);
    // merged-synopsis overlays (only valid when bigws)
    u16*   mbufA = (u16*)BIG;                            // 32MB
    u16*   mbufB = (u16*)(BIG + (size_t)32 * MB1);       // 32MB
    u16*   mx16  = (u16*)(BIG + (size_t)64 * MB1);       // 13.1MB
    u16*   mW16a = (u16*)(BIG + (size_t)78 * MB1);
    u16*   mW16b = (u16*)(BIG + (size_t)79 * MB1);

    auto cgrid = [](long n) { return dim3((unsigned)((n + 255) / 256)); };

    // ---- prep ----
    detect_k<<<dim3(1), dim3(256), 0, stream>>>(x_text, flagB);
    zero_k<<<cgrid(128 * 64), dim3(256), 0, stream>>>(cnts, 128 * 64);
    castbf_k<<<cgrid(MDU_ * H2), dim3(256), 0, stream>>>(W_cWh, 0, Wcwh16, MDU_ * H2, flagB);
    castbf_k<<<cgrid(MDU_ * H2), dim3(256), 0, stream>>>(W_cWu, 0, Wcwu16, MDU_ * H2, flagB);
    castbf_k<<<cgrid(MDU_ * H2), dim3(256), 0, stream>>>(W_Ws, 0, Wws16, MDU_ * H2, flagB);
    castbf_k<<<cgrid(TAGS_ * 1536), dim3(256), 0, stream>>>(W_out, 0, Wout16, TAGS_ * 1536, flagB);
    castf_k<<<cgrid(MDU_), dim3(256), 0, stream>>>(W_v, WvF, MDU_, flagB);
    castf_k<<<cgrid(TAGS_), dim3(256), 0, stream>>>(b_out, boutF, TAGS_, flagB);
    for (int l = 0; l < 6; ++l) {
        bias_sum_k<<<dim3(4), dim3(256), 0, stream>>>(bih[l], bhh[l], bsum[l], flagB);
        whh_frag_k<<<dim3(1024), dim3(256), 0, stream>>>(Whh[l], WF[l], flagB);
    }
    wsum_k<<<cgrid(H2 * H2), dim3(256), 0, stream>>>(W_sWh, W_sWu, WsumB, flagB);

    // ---- phase A: synopsis -> U ----  (groups 4..67)
    if (bigws) {
        // all 256 seqs in one pass: one gemm pair + ONE lstm dispatch (64 steps)
        castbf_k<<<cgrid(G4 * DD), dim3(256), 0, stream>>>(Wih[2], 0, mW16a, G4 * DD, flagB);
        castbf_k<<<cgrid(G4 * DD), dim3(256), 0, stream>>>(Wih[3], 0, mW16b, G4 * DD, flagB);
        castbf_k<<<cgrid((long)NSEQ * JJ * DD), dim3(256), 0, stream>>>(x_syn, 0, mx16, (long)NSEQ * JJ * DD, flagB);
        gemm_bt<<<dim3(8, (NSEQ * JJ) / BM), dim3(256), 0, stream>>>(mx16, DD, mW16a, DD, mbufA, G4, bsum[2], NSEQ * JJ, G4, DD, 1);
        gemm_bt<<<dim3(8, (NSEQ * JJ) / BM), dim3(256), 0, stream>>>(mx16, DD, mW16b, DD, mbufB, G4, bsum[3], NSEQ * JJ, G4, DD, 1);
        // 64 groups (2 dir x 32 bat) x 4 members, XCD-packed: G8=64, grid 256
        lstm_coop<<<dim3(256), dim3(256), 0, stream>>>(
            mbufA, mbufB, WF[2], WF[3], JJ,
            Ub, H2, (u16*)nullptr, 0, (const int*)nullptr,
            0, 1, 0, hx32, cnts, 4, 32, 64);
    } else {
        castbf_k<<<cgrid(G4 * DD), dim3(256), 0, stream>>>(Wih[2], 0, W16a, G4 * DD, flagB);
        castbf_k<<<cgrid(G4 * DD), dim3(256), 0, stream>>>(Wih[3], 0, W16b, G4 * DD, flagB);
        for (int c = 0; c < NSEQ / SCH; ++c) {
            long chunkElems = (long)SCH * JJ * DD;
            castbf_k<<<cgrid(chunkElems), dim3(256), 0, stream>>>(x_syn, (long)c * chunkElems, x16, chunkElems, flagB);
            gemm_bt<<<dim3(8, (SCH * JJ) / BM), dim3(256), 0, stream>>>(x16, DD, W16a, DD, bufA, G4, bsum[2], SCH * JJ, G4, DD, 1);
            gemm_bt<<<dim3(8, (SCH * JJ) / BM), dim3(256), 0, stream>>>(x16, DD, W16b, DD, bufB, G4, bsum[3], SCH * JJ, G4, DD, 1);
            // 16 groups (2 dir x 8 bat) x 4 members: G8=16, grid 64
            lstm_coop<<<dim3(64), dim3(256), 0, stream>>>(
                bufA, bufB, WF[2], WF[3], JJ,
                Ub, H2, (u16*)nullptr, 0, (const int*)nullptr,
                0, 1, c * SCH, hx32, cnts, 4 + c * 16, 8, 16);
        }
    }

    // ---- phase B: context layer-1 -> H (Gb left), m (mMb) ----  (groups 0,1)
    castbf_k<<<cgrid((long)BT * DD), dim3(256), 0, stream>>>(x_text, 0, x16, (long)BT * DD, flagB);
    castbf_k<<<cgrid(G4 * DD), dim3(256), 0, stream>>>(Wih[0], 0, W16a, G4 * DD, flagB);
    castbf_k<<<cgrid(G4 * DD), dim3(256), 0, stream>>>(Wih[1], 0, W16b, G4 * DD, flagB);
    gemm_bt<<<dim3(8, 32), dim3(256), 0, stream>>>(x16, DD, W16a, DD, bufA, G4, bsum[0], BT, G4, DD, 1);
    gemm_bt<<<dim3(8, 32), dim3(256), 0, stream>>>(x16, DD, W16b, DD, bufB, G4, bsum[1], BT, G4, DD, 1);
    // 2 groups (dirs) x 4 members, XCD-packed: G8=8, grid 32
    lstm_coop<<<dim3(32), dim3(256), 0, stream>>>(
        bufA, bufB, WF[0], WF[1], TT,
        Gb, G4, mMb, H2, len_ctx, 0, 0, 0, hx32, cnts, 0, 1, 8);

    // ---- phase C: attention ----
    gemm_bt<<<dim3(1, 32), dim3(256), 0, stream>>>(Gb, G4, Wcwh16, H2, cWhB, MDU_, nullptr, BT, MDU_, H2, 0);
    gemm_bt<<<dim3(1, 2),  dim3(256), 0, stream>>>(Ub, H2, Wcwu16, H2, cWuB, MDU_, nullptr, NSEQ, MDU_, H2, 0);
    hprev_k<<<cgrid(BT * H2), dim3(256), 0, stream>>>(Gb, HprevB);
    gemm_bt<<<dim3(4, 32), dim3(256), 0, stream>>>(HprevB, H2, WsumB, H2, eBuf, H2, nullptr, BT, H2, H2, 0);
    s_k<<<cgrid(BT * H2), dim3(256), 0, stream>>>(eBuf, mMb, sBuf);
    gemm_bt<<<dim3(1, 32), dim3(256), 0, stream>>>(sBuf, H2, Wws16, H2, sWB, MDU_, nullptr, BT, MDU_, H2, 0);
    z_k<<<cgrid(BT * SS), dim3(256), 0, stream>>>(cWhB, cWuB, WvF, zB);
    zhat_k<<<cgrid(BT), dim3(256), 0, stream>>>(sWB, cWhB, WvF, zhatB);
    attn_mix_k<<<dim3(BT), dim3(64), 0, stream>>>(zB, zhatB, Ub, sBuf, Gb);

    // ---- phase D: layer-2 LSTMs over G -> M (into mMb) ----  (groups 2,3)
    castbf_k<<<cgrid(G4 * G4), dim3(256), 0, stream>>>(Wih[4], 0, W16aD, G4 * G4, flagB);
    castbf_k<<<cgrid(G4 * G4), dim3(256), 0, stream>>>(Wih[5], 0, W16bD, G4 * G4, flagB);
    gemm_bt<<<dim3(8, 32), dim3(256), 0, stream>>>(Gb, G4, W16aD, G4, mxWf, G4, bsum[4], BT, G4, G4, 1);
    gemm_bt<<<dim3(8, 32), dim3(256), 0, stream>>>(Gb, G4, W16bD, G4, mxWb, G4, bsum[5], BT, G4, G4, 1);
    lstm_coop<<<dim3(32), dim3(256), 0, stream>>>(
        mxWf, mxWb, WF[4], WF[5], TT,
        mMb, H2, (u16*)nullptr, 0, (const int*)nullptr, 1, 0, 0, hx32, cnts, 2, 1, 8);

    // ---- output ----
    logit_k<<<dim3(BT / 4), dim3(256), 0, stream>>>(Gb, mMb, Wout16, boutF, d_out, flagB);
}